// Round 9
// baseline (716.167 us; speedup 1.0000x reference)
//
#include <hip/hip_runtime.h>
#include <hip/hip_bf16.h>
#include <math.h>

typedef __hip_bfloat16 bf16;
typedef float f32x4 __attribute__((ext_vector_type(4)));
typedef short short8 __attribute__((ext_vector_type(8)));
typedef unsigned short u16x4 __attribute__((ext_vector_type(4)));
typedef unsigned short u16x8 __attribute__((ext_vector_type(8)));

#define AS1 __attribute__((address_space(1)))
#define AS3 __attribute__((address_space(3)))

__device__ __forceinline__ void gload16(const void* g, void* l) {
  __builtin_amdgcn_global_load_lds((const AS1 unsigned int*)g, (AS3 unsigned int*)l, 16, 0, 0);
}
__device__ __forceinline__ float b2f(unsigned short u) {
  union { unsigned int i; float f; } c; c.i = ((unsigned int)u) << 16; return c.f;
}
__device__ __forceinline__ unsigned short f2b(float f) {
  bf16 h = __float2bfloat16(f);
  unsigned short s; __builtin_memcpy(&s, &h, 2); return s;
}
__device__ __forceinline__ f32x4 mfma16(short8 a, short8 b, f32x4 c) {
  return __builtin_amdgcn_mfma_f32_16x16x32_bf16(a, b, c, 0, 0, 0);
}

#define BARR asm volatile("s_barrier" ::: "memory")
#define LGKM0 asm volatile("s_waitcnt lgkmcnt(0)" ::: "memory")
#define VM8 asm volatile("s_waitcnt vmcnt(8)" ::: "memory")
#define VM4 asm volatile("s_waitcnt vmcnt(4)" ::: "memory")
#define VM3 asm volatile("s_waitcnt vmcnt(3)" ::: "memory")
#define VM0 asm volatile("s_waitcnt vmcnt(0)" ::: "memory")
#define SB0 __builtin_amdgcn_sched_barrier(0)
#define PRIO1 __builtin_amdgcn_s_setprio(1)
#define PRIO0 __builtin_amdgcn_s_setprio(0)

// ---------------- LayerNorm: f32 in -> bf16 out, one block per 1024-wide row ----------------
__global__ __launch_bounds__(256) void ln_kernel(
    const float* __restrict__ X, const float* __restrict__ G,
    const float* __restrict__ Bb, unsigned short* __restrict__ Y) {
  __shared__ float red[8];
  const size_t row = blockIdx.x;
  const int tid = threadIdx.x;
  f32x4 v = *(const f32x4*)&X[row * 1024 + tid * 4];
  float s = 0.f, sq = 0.f;
#pragma unroll
  for (int j = 0; j < 4; ++j) { s += v[j]; sq += v[j] * v[j]; }
#pragma unroll
  for (int o = 1; o < 64; o <<= 1) { s += __shfl_xor(s, o); sq += __shfl_xor(sq, o); }
  if ((tid & 63) == 0) { red[tid >> 6] = s; red[4 + (tid >> 6)] = sq; }
  __syncthreads();
  s = red[0] + red[1] + red[2] + red[3];
  sq = red[4] + red[5] + red[6] + red[7];
  const float mean = s * (1.f / 1024.f);
  const float var = sq * (1.f / 1024.f) - mean * mean;
  const float inv = 1.f / sqrtf(var + 1e-5f);
  f32x4 gv = *(const f32x4*)&G[tid * 4];
  f32x4 bv = *(const f32x4*)&Bb[tid * 4];
  u16x4 ov;
#pragma unroll
  for (int j = 0; j < 4; ++j) ov[j] = f2b((v[j] - mean) * inv * gv[j] + bv[j]);
  *(u16x4*)&Y[row * 1024 + tid * 4] = ov;
}

// ---------------- Weight transpose: f32 src[K][N] -> bf16 dst[n][dld] (+doff) ----------------
__global__ __launch_bounds__(256) void transpose_w(
    const float* __restrict__ S, unsigned short* __restrict__ D,
    int N, int dld, int doff) {
  __shared__ __attribute__((aligned(16))) unsigned short t[64][72];
  const int k0 = blockIdx.x * 64, n0 = blockIdx.y * 64;
  const int tid = threadIdx.x;
#pragma unroll
  for (int i = 0; i < 2; ++i) {
    int c = i * 256 + tid;
    int row = c >> 3, c8 = c & 7;
    f32x4 a = *(const f32x4*)&S[(size_t)(k0 + row) * N + n0 + c8 * 8];
    f32x4 b = *(const f32x4*)&S[(size_t)(k0 + row) * N + n0 + c8 * 8 + 4];
    u16x8 o;
#pragma unroll
    for (int j = 0; j < 4; ++j) { o[j] = f2b(a[j]); o[4 + j] = f2b(b[j]); }
    *(u16x8*)&t[row][c8 * 8] = o;
  }
  __syncthreads();
#pragma unroll
  for (int i = 0; i < 2; ++i) {
    int c = i * 256 + tid;
    int nrow = c >> 3, k8 = c & 7;
    u16x8 o;
#pragma unroll
    for (int j = 0; j < 8; ++j) o[j] = t[k8 * 8 + j][nrow];
    *(u16x8*)&D[(size_t)(n0 + nrow) * dld + doff + k0 + k8 * 8] = o;
  }
}

__global__ __launch_bounds__(256) void bias_comb(
    const float* __restrict__ a, const float* __restrict__ b, float* __restrict__ o) {
  int i = blockIdx.x * 256 + threadIdx.x;
  o[i] = a[i] + b[i];
}

// concat bias: o[0..2N) = a | b
__global__ __launch_bounds__(256) void bias_cat(
    const float* __restrict__ a, const float* __restrict__ b, float* __restrict__ o, int N) {
  int i = blockIdx.x * 256 + threadIdx.x;
  o[i] = (i < N) ? a[i] : b[i - N];
}

#define EPI_STORE 0
#define EPI_GELU 1
#define EPI_RES 2

// ---------------- GEMM v9-big: 256x256, BK=64, counted-vmcnt, B in REGISTERS ----------------
// R7 structure (2-D grid, no swizzle — R8 proved swizzle tripled FETCH) with Bbuf removed:
// B fragments are loaded global->VGPR with PLAIN HIP loads (compiler tracks them and inserts
// its own vmcnt before each use — correctness never depends on manual counting of B).
// Manual counted waits cover only the A global_load_lds stream:
//   prologue: issue A(0,k0), B(0,k0), A(0,k1) -> VM4 retires A(0,k0)+B(0,k0), leaves A(0,k1).
//   steady:   each phase issues {4 B-loads, 4 A-stages}; end-of-phase VM8 retires exactly the
//             previous phase's 8-issue group (A read next phase, B already consumed/covered).
//   tail:     last tile: phase(T,0) VM0, phase(T,1) no wait.
// Effects vs R7: LDS 128->64 KB, LDS traffic/phase 160->80 KB, ds_read/phase 12->8.
// K-accumulation order unchanged -> numerics identical.
template <int EPI, int OF32>
__global__ __launch_bounds__(512, 2) void gemm_big(
    const unsigned short* __restrict__ A, const unsigned short* __restrict__ Bt,
    const float* __restrict__ bias, void* __restrict__ Cv,
    const float* __restrict__ res, int K, int ldA, int ldC) {
  __shared__ __attribute__((aligned(16))) unsigned short Abuf[2][2][16 * 512];
  const int tid = threadIdx.x, lane = tid & 63, wv = tid >> 6;
  const int g = lane >> 4, r = lane & 15;
  const int wr = wv >> 2, wc = wv & 3;
  const size_t arow0 = (size_t)blockIdx.x * 256;
  const size_t brow0 = (size_t)blockIdx.y * 256;
  const size_t ldAs = (size_t)ldA, Ksz = (size_t)K;
  // A frag f: rows f*16+(l&15), k kk*32+(l>>4)*8; wave wv stages frags {2wv, 2wv+1}
  const unsigned short* gA0 = A + (arow0 + (size_t)((2 * wv + 0) * 16 + r)) * ldAs + g * 8;
  const unsigned short* gA1 = A + (arow0 + (size_t)((2 * wv + 1) * 16 + r)) * ldAs + g * 8;
  // B frag bases for this wave's 4 n-subtiles (per-lane addresses, 16B-aligned)
  const unsigned short* gBr0 = Bt + (brow0 + (size_t)(wc * 64 + 0 * 16 + r)) * Ksz + g * 8;
  const unsigned short* gBr1 = Bt + (brow0 + (size_t)(wc * 64 + 1 * 16 + r)) * Ksz + g * 8;
  const unsigned short* gBr2 = Bt + (brow0 + (size_t)(wc * 64 + 2 * 16 + r)) * Ksz + g * 8;
  const unsigned short* gBr3 = Bt + (brow0 + (size_t)(wc * 64 + 3 * 16 + r)) * Ksz + g * 8;
  const int nT = K >> 6;
  f32x4 acc[8][4] = {};
  short8 af[8];
  short8 bE[4], bO[4];  // B frags for (.,kk0) phases / (.,kk1) phases

#define BLD(DST, OFF) do { size_t o_ = (OFF);                                        \
    DST[0] = *(const short8*)(gBr0 + o_);                                            \
    DST[1] = *(const short8*)(gBr1 + o_);                                            \
    DST[2] = *(const short8*)(gBr2 + o_);                                            \
    DST[3] = *(const short8*)(gBr3 + o_); } while (0)
#define STGA(BUF, KK, T_) do { size_t o_ = (size_t)(T_) * 64 + (KK) * 32;            \
    gload16(gA0 + o_, &Abuf[BUF][KK][(2 * wv + 0) * 512]);                           \
    gload16(gA1 + o_, &Abuf[BUF][KK][(2 * wv + 1) * 512]); } while (0)
#define RDA(CUR, KK) _Pragma("unroll") for (int m_ = 0; m_ < 8; ++m_)                \
    af[m_] = *(const short8*)&Abuf[CUR][KK][(wr * 8 + m_) * 512 + lane * 8];
#define MMQ(BB) _Pragma("unroll") for (int m_ = 0; m_ < 8; ++m_)                     \
    _Pragma("unroll") for (int n_ = 0; n_ < 4; ++n_)                                 \
      acc[m_][n_] = mfma16(af[m_], BB[n_], acc[m_][n_]);

  // prologue (issue order matters for VM4: A(0,k0), B(0,k0), A(0,k1))
  STGA(0, 0, 0);
  BLD(bE, 0);
  STGA(0, 1, 0);
  VM4; BARR; SB0;

  for (int T = 0; T < nT; ++T) {
    const int cur = T & 1;
    const bool s1 = (T + 1) < nT;
    // phase (T,0): use bE; load bO = B(T,kk1); stage A(T+1,kk0)
    RDA(cur, 0);
    BLD(bO, (size_t)T * 64 + 32);
    if (s1) STGA(cur ^ 1, 0, T + 1);
    BARR; LGKM0; SB0;
    PRIO1; MMQ(bE); PRIO0;
    if (s1) { VM8; } else { VM0; }
    BARR; SB0;
    // phase (T,1): use bO; load bE = B(T+1,kk0); stage A(T+1,kk1)
    RDA(cur, 1);
    if (s1) { BLD(bE, (size_t)(T + 1) * 64); STGA(cur ^ 1, 1, T + 1); }
    BARR; LGKM0; SB0;
    PRIO1; MMQ(bO); PRIO0;
    if (s1) { VM8; }
    BARR; SB0;
  }
#undef BLD
#undef STGA
#undef RDA
#undef MMQ

#pragma unroll
  for (int m = 0; m < 8; ++m) {
#pragma unroll
    for (int n = 0; n < 4; ++n) {
      const int col = (int)brow0 + wc * 64 + n * 16 + r;
      const float bv = bias[col];
#pragma unroll
      for (int i = 0; i < 4; ++i) {
        const size_t row = arow0 + wr * 128 + m * 16 + g * 4 + i;
        float v = acc[m][n][i] + bv;
        if (EPI == EPI_GELU) v = 0.5f * v * (1.f + erff(v * 0.70710678118f));
        if (EPI == EPI_RES) v += res[row * ldC + col];
        if (OF32) ((float*)Cv)[row * ldC + col] = v;
        else ((unsigned short*)Cv)[row * ldC + col] = f2b(v);
      }
    }
  }
}

// ---------------- GEMM v8-small: 128x256, BK=32 phases, ring-3 LDS, 2 blocks/CU -----------
// 8 waves (2M x 4N), per-wave 64x64, launch_bounds(512,4) -> 2 blocks/CU (72 KB LDS x 2).
// Ring-3 of 24KB kk-groups: phase p reads region p%3, stages p+2 into (p+2)%3; phase-end
// vmcnt(3) retires exactly group p+1 (never drains in steady state). Unchanged from R8.
template <int EPI, int OF32>
__global__ __launch_bounds__(512, 4) void gemm_sml(
    const unsigned short* __restrict__ A, const unsigned short* __restrict__ Bt,
    const float* __restrict__ bias, void* __restrict__ Cv,
    const float* __restrict__ res, int K, int ldA, int ldC, int lgnmt) {
  __shared__ __attribute__((aligned(16))) unsigned short Abuf[3][8 * 512];
  __shared__ __attribute__((aligned(16))) unsigned short Bbuf[3][16 * 512];
  const int tid = threadIdx.x, lane = tid & 63, wv = tid >> 6;
  const int g = lane >> 4, r = lane & 15;
  const int wr = wv >> 2, wc = wv & 3;
  const int bid = blockIdx.x, nwg = gridDim.x;
  const int swz = (bid & 7) * (nwg >> 3) + (bid >> 3);  // XCD-aware (nwg % 8 == 0)
  const int mt = swz & ((1 << lgnmt) - 1), nt = swz >> lgnmt;
  const size_t arow0 = (size_t)mt * 128;
  const size_t brow0 = (size_t)nt * 256;
  const size_t ldAs = (size_t)ldA, Ksz = (size_t)K;
  const unsigned short* gAs = A + (arow0 + (size_t)(wv * 16 + r)) * ldAs + g * 8;
  const unsigned short* gB0 = Bt + (brow0 + (size_t)((2 * wv + 0) * 16 + r)) * Ksz + g * 8;
  const unsigned short* gB1 = Bt + (brow0 + (size_t)((2 * wv + 1) * 16 + r)) * Ksz + g * 8;
  const int nP = K >> 5;  // phases of K=32; nP >= 3 at all call sites
  f32x4 acc[4][4] = {};

#define STG(RG, P_) do { size_t o_ = (size_t)(P_) * 32;                              \
    gload16(gAs + o_, &Abuf[RG][wv * 512]);                                          \
    gload16(gB0 + o_, &Bbuf[RG][(2 * wv + 0) * 512]);                                \
    gload16(gB1 + o_, &Bbuf[RG][(2 * wv + 1) * 512]); } while (0)

  // prologue: stage groups 0,1; retire group 0 (group 1's 3 loads stay in flight)
  STG(0, 0); STG(1, 1);
  VM3; BARR; SB0;

  int rc = 0;  // region of current phase = p % 3
  for (int p = 0; p < nP; ++p) {
    const bool s2 = (p + 2) < nP;
    const bool s1 = (p + 1) < nP;
    int rs = rc + 2; if (rs >= 3) rs -= 3;  // region for p+2
    short8 af[4], bfr[4];
#pragma unroll
    for (int m = 0; m < 4; ++m)
      af[m] = *(const short8*)&Abuf[rc][(wr * 4 + m) * 512 + lane * 8];
#pragma unroll
    for (int n = 0; n < 4; ++n)
      bfr[n] = *(const short8*)&Bbuf[rc][(wc * 4 + n) * 512 + lane * 8];
    if (s2) STG(rs, p + 2);
    BARR; LGKM0; SB0;
    PRIO1;
#pragma unroll
    for (int m = 0; m < 4; ++m)
#pragma unroll
      for (int n = 0; n < 4; ++n)
        acc[m][n] = mfma16(af[m], bfr[n], acc[m][n]);
    PRIO0;
    if (s2) { VM3; } else if (s1) { VM0; }
    BARR; SB0;
    rc = (rc + 1 == 3) ? 0 : rc + 1;
  }
#undef STG

#pragma unroll
  for (int m = 0; m < 4; ++m) {
#pragma unroll
    for (int n = 0; n < 4; ++n) {
      const int col = (int)brow0 + wc * 64 + n * 16 + r;
      const float bv = bias[col];
#pragma unroll
      for (int i = 0; i < 4; ++i) {
        const size_t row = arow0 + wr * 64 + m * 16 + g * 4 + i;
        float v = acc[m][n][i] + bv;
        if (EPI == EPI_GELU) v = 0.5f * v * (1.f + erff(v * 0.70710678118f));
        if (EPI == EPI_RES) v += res[row * ldC + col];
        if (OF32) ((float*)Cv)[row * ldC + col] = v;
        else ((unsigned short*)Cv)[row * ldC + col] = f2b(v);
      }
    }
  }
}

// ---------------- Sliding-window attention: one wg per (b,h,qblock of 128) ----------------
// qkv layout: [8192][6144] bf16 (fused QKV buffer, attention half at cols 0..3071):
// q = cols 0..1023, k = 1024..2047, v = 2048..3071, head h at h*64.
__global__ __launch_bounds__(256) void swa_kernel(
    const unsigned short* __restrict__ qkv, unsigned short* __restrict__ outc) {
  __shared__ __attribute__((aligned(16))) unsigned short Ks[256 * 64];   // swizzled [s][e]
  __shared__ __attribute__((aligned(16))) unsigned short Vt[64 * 264];   // [e][s]
  __shared__ __attribute__((aligned(16))) unsigned short Ps[128 * 264];  // [r][s]
  __shared__ __attribute__((aligned(16))) float dn[128];
  const int bid = blockIdx.x;
  const int qb = bid & 31, h = (bid >> 5) & 15, b = bid >> 9;
  const long btok = (long)b * 4096;
  const long tok0 = btok + (long)qb * 128;
  const int tid = threadIdx.x, lane = tid & 63, wv = tid >> 6;
  const int g = lane >> 4, r = lane & 15;

#pragma unroll
  for (int i = 0; i < 8; ++i) {  // K stage: 16B chunks, chunk-XOR swizzle over 8 chunks/row
    int chunk = (wv * 8 + i) * 64 + lane;
    int s = chunk >> 3, cc = (chunk & 7) ^ (s & 7);
    long kt = tok0 - 128 + s; if (kt < btok) kt = btok;  // block 0: masked anyway
    gload16(&qkv[(size_t)kt * 6144 + 1024 + h * 64 + cc * 8], &Ks[(wv * 8 + i) * 512]);
  }
#pragma unroll
  for (int i = 0; i < 8; ++i) {  // V transposed stage
    int chunk = i * 256 + tid;
    int s = chunk >> 3, e8 = chunk & 7;
    long kt = tok0 - 128 + s; if (kt < btok) kt = btok;
    u16x8 u = *(const u16x8*)&qkv[(size_t)kt * 6144 + 2048 + h * 64 + e8 * 8];
#pragma unroll
    for (int j = 0; j < 8; ++j) Vt[(e8 * 8 + j) * 264 + s] = u[j];
  }
  short8 qf[2][2];  // Q frags direct from global
#pragma unroll
  for (int m = 0; m < 2; ++m)
#pragma unroll
    for (int kc = 0; kc < 2; ++kc)
      qf[m][kc] = *(const short8*)&qkv[(size_t)(tok0 + wv * 32 + m * 16 + r) * 6144 + h * 64 + kc * 32 + g * 8];
  __syncthreads();

  float rs[2][4] = {};
  for (int n = 0; n < 16; ++n) {
    const int srow = n * 16 + r;
    short8 kf0 = *(const short8*)&Ks[srow * 64 + ((g) ^ (srow & 7)) * 8];
    short8 kf1 = *(const short8*)&Ks[srow * 64 + ((4 + g) ^ (srow & 7)) * 8];
#pragma unroll
    for (int m = 0; m < 2; ++m) {
      f32x4 acc = {0.f, 0.f, 0.f, 0.f};
      acc = mfma16(qf[m][0], kf0, acc);
      acc = mfma16(qf[m][1], kf1, acc);
#pragma unroll
      for (int i = 0; i < 4; ++i) {
        int rr = wv * 32 + m * 16 + g * 4 + i;
        int ss = n * 16 + r;
        bool valid = (ss >= rr + 1) && (ss <= rr + 128) && (qb > 0 || ss >= 128);
        float p = valid ? __expf(acc[i] * 0.125f) : 0.f;  // scores small: no max-sub needed
        rs[m][i] += p;
        Ps[rr * 264 + ss] = f2b(p);
      }
    }
  }
#pragma unroll
  for (int m = 0; m < 2; ++m)
#pragma unroll
    for (int i = 0; i < 4; ++i) {
      float v = rs[m][i];
      v += __shfl_xor(v, 1); v += __shfl_xor(v, 2);
      v += __shfl_xor(v, 4); v += __shfl_xor(v, 8);
      if (r == i) dn[wv * 32 + m * 16 + g * 4 + i] = v;
    }
  __syncthreads();

  f32x4 oacc[2][4] = {};
  for (int sc = 0; sc < 8; ++sc) {
    short8 pf[2], vf[4];
#pragma unroll
    for (int m = 0; m < 2; ++m)
      pf[m] = *(const short8*)&Ps[(wv * 32 + m * 16 + r) * 264 + sc * 32 + g * 8];
#pragma unroll
    for (int n = 0; n < 4; ++n)
      vf[n] = *(const short8*)&Vt[(n * 16 + r) * 264 + sc * 32 + g * 8];
#pragma unroll
    for (int m = 0; m < 2; ++m)
#pragma unroll
      for (int n = 0; n < 4; ++n)
        oacc[m][n] = mfma16(pf[m], vf[n], oacc[m][n]);
  }
#pragma unroll
  for (int m = 0; m < 2; ++m) {
    f32x4 dv = *(const f32x4*)&dn[wv * 32 + m * 16 + g * 4];
#pragma unroll
    for (int n = 0; n < 4; ++n) {
      int col = h * 64 + n * 16 + r;
#pragma unroll
      for (int i = 0; i < 4; ++i) {
        size_t row = (size_t)(tok0 + wv * 32 + m * 16 + g * 4 + i);
        outc[row * 2048 + col] = f2b(oacc[m][n][i] / dv[i]);
      }
    }
  }
}

// ---------------- Linear attention pass 1: per-chunk KVt[f][e], kz[e] ----------------
// qkv points at the S-half (fused buffer + 3072), row stride 6144.
__global__ __launch_bounds__(256) void lin_pass1(
    const unsigned short* __restrict__ qkv, float* __restrict__ KVt, float* __restrict__ kz) {
  __shared__ __attribute__((aligned(16))) unsigned short kf[128 * 72];
  __shared__ __attribute__((aligned(16))) unsigned short vs[128 * 72];
  const int bid = blockIdx.x;
  const int ch = bid & 31, h = (bid >> 5) & 15, b = bid >> 9;
  const size_t tok0 = (size_t)b * 4096 + (size_t)ch * 128;
  const int tid = threadIdx.x;
#pragma unroll
  for (int i = 0; i < 4; ++i) {
    int c = i * 256 + tid;
    int row = c >> 3, e8 = c & 7;
    u16x8 uk = *(const u16x8*)&qkv[(tok0 + row) * 6144 + 1024 + h * 64 + e8 * 8];
    u16x8 uv = *(const u16x8*)&qkv[(tok0 + row) * 6144 + 2048 + h * 64 + e8 * 8];
    u16x8 tk;
#pragma unroll
    for (int j = 0; j < 8; ++j) {
      float x = b2f(uk[j]);
      x = (x > 0.f) ? x : expm1f(x);  // elu
      tk[j] = f2b(x + 1.0001f);
    }
    *(u16x8*)&kf[row * 72 + e8 * 8] = tk;
    *(u16x8*)&vs[row * 72 + e8 * 8] = uv;
  }
  __syncthreads();
  const int e0 = (tid & 15) * 4, f0 = (tid >> 4) * 4;
  float acc[4][4] = {};
  for (int c = 0; c < 128; ++c) {
    u16x4 ku = *(const u16x4*)&kf[c * 72 + e0];
    u16x4 vu = *(const u16x4*)&vs[c * 72 + f0];
    float ke[4], vv[4];
#pragma unroll
    for (int j = 0; j < 4; ++j) { ke[j] = b2f(ku[j]); vv[j] = b2f(vu[j]); }
#pragma unroll
    for (int jf = 0; jf < 4; ++jf)
#pragma unroll
      for (int je = 0; je < 4; ++je)
        acc[jf][je] += vv[jf] * ke[je];
  }
  const size_t base = (size_t)bid * 4096;
#pragma unroll
  for (int jf = 0; jf < 4; ++jf) {
    f32x4 o = {acc[jf][0], acc[jf][1], acc[jf][2], acc[jf][3]};
    *(f32x4*)&KVt[base + (f0 + jf) * 64 + e0] = o;
  }
  if (tid < 64) {
    float s = 0.f;
    for (int c = 0; c < 128; ++c) s += b2f(kf[c * 72 + tid]);
    kz[(size_t)bid * 64 + tid] = s;
  }
}

// ---------------- pass 2: per (b,h) exclusive prefix over 32 chunks (in place) ----------------
__global__ __launch_bounds__(256) void lin_pass2(float* __restrict__ KVt, float* __restrict__ kz) {
  const int bh = blockIdx.x;
  const int tid = threadIdx.x;
  f32x4 run[4] = {};
  for (int ch = 0; ch < 32; ++ch) {
    const size_t base = ((size_t)bh * 32 + ch) * 4096;
#pragma unroll
    for (int i = 0; i < 4; ++i) {
      float* p = &KVt[base + (size_t)(i * 256 + tid) * 4];
      f32x4 c = *(f32x4*)p;
      *(f32x4*)p = run[i];
      run[i] += c;
    }
  }
  if (tid < 64) {
    float rz = 0.f;
    for (int ch = 0; ch < 32; ++ch) {
      float* p = &kz[((size_t)bh * 32 + ch) * 64 + tid];
      float c = *p; *p = rz; rz += c;
    }
  }
}

// ---------------- pass 3: o = (q@S_prev + tril(qk^T)@v) / (q.z_prev + rowsumA + 1e-6) ----------------
__global__ __launch_bounds__(256) void lin_pass3(
    const unsigned short* __restrict__ qkv, const float* __restrict__ KVt,
    const float* __restrict__ kz, unsigned short* __restrict__ outc) {
  __shared__ __attribute__((aligned(16))) unsigned short qf[128 * 72];
  __shared__ __attribute__((aligned(16))) unsigned short kf[128 * 72];
  __shared__ __attribute__((aligned(16))) unsigned short vt[64 * 136];
  __shared__ __attribute__((aligned(16))) unsigned short st[64 * 72];
  __shared__ __attribute__((aligned(16))) unsigned short am[128 * 136];
  __shared__ __attribute__((aligned(16))) float zs[64];
  __shared__ __attribute__((aligned(16))) float dnl[128];
  const int bid = blockIdx.x;
  const int ch = bid & 31, h = (bid >> 5) & 15, b = bid >> 9;
  const size_t tok0 = (size_t)b * 4096 + (size_t)ch * 128;
  const int tid = threadIdx.x, lane = tid & 63, wv = tid >> 6;
  const int g = lane >> 4, r = lane & 15;

#pragma unroll
  for (int i = 0; i < 4; ++i) {
    int c = i * 256 + tid;
    int row = c >> 3, e8 = c & 7;
    u16x8 uq = *(const u16x8*)&qkv[(tok0 + row) * 6144 + h * 64 + e8 * 8];
    u16x8 uk = *(const u16x8*)&qkv[(tok0 + row) * 6144 + 1024 + h * 64 + e8 * 8];
    u16x8 uv = *(const u16x8*)&qkv[(tok0 + row) * 6144 + 2048 + h * 64 + e8 * 8];
    u16x8 tq, tk;
#pragma unroll
    for (int j = 0; j < 8; ++j) {
      float x = b2f(uq[j]) * 0.125f;
      x = (x > 0.f) ? x : expm1f(x);
      tq[j] = f2b(x + 1.0001f);
      float y = b2f(uk[j]);
      y = (y > 0.f) ? y : expm1f(y);
      tk[j] = f2b(y + 1.0001f);
    }
    *(u16x8*)&qf[row * 72 + e8 * 8] = tq;
    *(u16x8*)&kf[row * 72 + e8 * 8] = tk;
#pragma unroll
    for (int j = 0; j < 8; ++j) vt[(e8 * 8 + j) * 136 + row] = uv[j];
  }
#pragma unroll
  for (int i = 0; i < 2; ++i) {  // S_prev^T (f-major) f32 -> bf16 LDS
    int idx = i * 256 + tid;
    int f = idx >> 3, e8 = idx & 7;
    f32x4 s0 = *(const f32x4*)&KVt[(size_t)bid * 4096 + f * 64 + e8 * 8];
    f32x4 s1 = *(const f32x4*)&KVt[(size_t)bid * 4096 + f * 64 + e8 * 8 + 4];
    u16x8 t;
#pragma unroll
    for (int j = 0; j < 4; ++j) { t[j] = f2b(s0[j]); t[4 + j] = f2b(s1[j]); }
    *(u16x8*)&st[f * 72 + e8 * 8] = t;
  }
  if (tid < 64) zs[tid] = kz[(size_t)bid * 64 + tid];
  __syncthreads();

  short8 aq[2][2];
#pragma unroll
  for (int m = 0; m < 2; ++m)
#pragma unroll
    for (int kc = 0; kc < 2; ++kc)
      aq[m][kc] = *(const short8*)&qf[(wv * 32 + m * 16 + r) * 72 + kc * 32 + g * 8];

  float rsA[2][4] = {};
  for (int n = 0; n < 8; ++n) {  // A = tril(qf @ kf^T), bf16 to LDS + rowsums
    short8 bk0 = *(const short8*)&kf[(n * 16 + r) * 72 + g * 8];
    short8 bk1 = *(const short8*)&kf[(n * 16 + r) * 72 + 32 + g * 8];
#pragma unroll
    for (int m = 0; m < 2; ++m) {
      f32x4 acc = {0.f, 0.f, 0.f, 0.f};
      acc = mfma16(aq[m][0], bk0, acc);
      acc = mfma16(aq[m][1], bk1, acc);
#pragma unroll
      for (int i = 0; i < 4; ++i) {
        int rr = wv * 32 + m * 16 + g * 4 + i;
        int cc = n * 16 + r;
        float v = (cc <= rr) ? acc[i] : 0.f;
        rsA[m][i] += v;
        am[rr * 136 + cc] = f2b(v);
      }
    }
  }
#pragma unroll
  for (int m = 0; m < 2; ++m)
#pragma unroll
    for (int i = 0; i < 4; ++i) {
      float v = rsA[m][i];
      v += __shfl_xor(v, 1); v += __shfl_xor(v, 2);
      v += __shfl_xor(v, 4); v += __shfl_xor(v, 8);
      if (r == i) dnl[wv * 32 + m * 16 + g * 4 + i] = v;
    }
  __syncthreads();

  if (tid < 128) {  // den = rowsumA + qf . z_prev
    float s = dnl[tid];
#pragma unroll
    for (int e = 0; e < 64; e += 4) {
      u16x4 qv = *(const u16x4*)&qf[tid * 72 + e];
      s += b2f(qv[0]) * zs[e] + b2f(qv[1]) * zs[e + 1] + b2f(qv[2]) * zs[e + 2] + b2f(qv[3]) * zs[e + 3];
    }
    dnl[tid] = s + 1e-6f;
  }

  f32x4 oac[2][4] = {};
#pragma unroll
  for (int kc = 0; kc < 2; ++kc) {  // num += qf @ S_prev
    short8 sf[4];
#pragma unroll
    for (int n = 0; n < 4; ++n) sf[n] = *(const short8*)&st[(n * 16 + r) * 72 + kc * 32 + g * 8];
#pragma unroll
    for (int m = 0; m < 2; ++m)
#pragma unroll
      for (int n = 0; n < 4; ++n)
        oac[m][n] = mfma16(aq[m][kc], sf[n], oac[m][n]);
  }
  for (int c4 = 0; c4 < 4; ++c4) {  // num += A @ v
    short8 pa[2], vb[4];
#pragma unroll
    for (int m = 0; m < 2; ++m)
      pa[m] = *(const short8*)&am[(wv * 32 + m * 16 + r) * 136 + c4 * 32 + g * 8];
#pragma unroll
    for (int n = 0; n < 4; ++n)
      vb[n] = *(const short8*)&vt[(n * 16 + r) * 136 + c4 * 32 + g * 8];
#pragma unroll
    for (int m = 0; m < 2; ++m)
#pragma unroll
      for (int n = 0; n < 4; ++n)
        oac[m][n] = mfma16(pa[m], vb[n], oac[m][n]);
  }
  __syncthreads();
#pragma unroll
  for (int m = 0; m < 2; ++m) {
    f32x4 dv = *(const f32x4*)&dnl[wv * 32 + m * 16 + g * 4];
#pragma unroll
    for (int n = 0; n < 4; ++n) {
      int col = 1024 + h * 64 + n * 16 + r;
#pragma unroll
      for (int i = 0; i < 4; ++i) {
        size_t row = tok0 + wv * 32 + m * 16 + g * 4 + i;
        outc[row * 2048 + col] = f2b(oac[m][n][i] / dv[i]);
      }
    }
  }
}

// ---------------- host ----------------
extern "C" void kernel_launch(void* const* d_in, const int* in_sizes, int n_in,
                              void* d_out, int out_size, void* d_ws, size_t ws_size,
                              hipStream_t stream) {
  (void)in_sizes; (void)n_in; (void)out_size; (void)ws_size;
  const float* x      = (const float*)d_in[0];
  const float* g1     = (const float*)d_in[1];
  const float* b1     = (const float*)d_in[2];
  const float* Wqkv_a = (const float*)d_in[3];
  const float* bqkv_a = (const float*)d_in[4];
  const float* Wp_a   = (const float*)d_in[5];
  const float* bp_a   = (const float*)d_in[6];
  const float* Wqkv_s = (const float*)d_in[7];
  const float* bqkv_s = (const float*)d_in[8];
  const float* Wo_s   = (const float*)d_in[9];
  const float* bo_s   = (const float*)d_in[10];
  const float* Wo     = (const float*)d_in[11];
  const float* bo     = (const float*)d_in[12];
  const float* gm     = (const float*)d_in[13];
  const float* bm     = (const float*)d_in[14];
  const float* W1     = (const float*)d_in[15];
  const float* b1m    = (const float*)d_in[16];
  const float* W2     = (const float*)d_in[17];
  const float* b2m    = (const float*)d_in[18];
  float* out = (float*)d_out;

  char* ws = (char*)d_ws;
  size_t off = 0;
  auto alloc = [&](size_t bytes) { char* p = ws + off; off += (bytes + 255) & ~(size_t)255; return p; };
  unsigned short* wTaS  = (unsigned short*)alloc((size_t)6144 * 1024 * 2);  // [Wqkv_a^T ; Wqkv_s^T]
  unsigned short* wTpo  = (unsigned short*)alloc((size_t)1024 * 2048 * 2);
  unsigned short* wTo   = (unsigned short*)alloc((size_t)1024 * 1024 * 2);
  unsigned short* wT1   = (unsigned short*)alloc((size_t)4096 * 1024 * 2);
  unsigned short* wT2   = (unsigned short*)alloc((size_t)1024 * 4096 * 2);
  float*          bcomb = (float*)alloc(1024 * 4);
  float*          bcat  = (float*)alloc(6144 * 4);
  unsigned short* xn    = (unsigned short*)alloc((size_t)8192 * 1024 * 2);  // reused as h
  unsigned short* qkvAS = (unsigned short*)alloc((size_t)8192 * 6144 * 2);  // fused; reused as gbuf
  unsigned short* comb  = (unsigned short*)alloc((size_t)8192 * 2048 * 2);  // reused as x1 (f32)
  float*          kvt   = (float*)alloc((size_t)1024 * 4096 * 4);           // reused as sum (bf16)
  float*          kzp   = (float*)alloc((size_t)1024 * 64 * 4);
  unsigned short* gbuf  = qkvAS;
  unsigned short* sum   = (unsigned short*)kvt;
  unsigned short* h_    = xn;
  float*          x1    = (float*)comb;  // comb dead once sum is computed

  transpose_w<<<dim3(16, 48), 256, 0, stream>>>(Wqkv_a, wTaS, 3072, 1024, 0);
  transpose_w<<<dim3(16, 48), 256, 0, stream>>>(Wqkv_s, wTaS + (size_t)3072 * 1024, 3072, 1024, 0);
  transpose_w<<<dim3(16, 16), 256, 0, stream>>>(Wp_a, wTpo, 1024, 2048, 0);
  transpose_w<<<dim3(16, 16), 256, 0, stream>>>(Wo_s, wTpo, 1024, 2048, 1024);
  transpose_w<<<dim3(16, 16), 256, 0, stream>>>(Wo, wTo, 1024, 1024, 0);
  transpose_w<<<dim3(16, 64), 256, 0, stream>>>(W1, wT1, 4096, 1024, 0);
  transpose_w<<<dim3(64, 16), 256, 0, stream>>>(W2, wT2, 1024, 4096, 0);
  bias_comb<<<4, 256, 0, stream>>>(bp_a, bo_s, bcomb);
  bias_cat<<<24, 256, 0, stream>>>(bqkv_a, bqkv_s, bcat, 3072);

  ln_kernel<<<8192, 256, 0, stream>>>(x, g1, b1, xn);
  // fused QKV: M=8192, N=6144, K=1024 -> big 256x256, 2-D grid (R7 ordering, no swizzle)
  gemm_big<EPI_STORE, 0><<<dim3(32, 24), 512, 0, stream>>>(xn, wTaS, bcat, qkvAS, nullptr, 1024, 1024, 6144);
  swa_kernel<<<1024, 256, 0, stream>>>(qkvAS, comb);
  lin_pass1<<<1024, 256, 0, stream>>>(qkvAS + 3072, kvt, kzp);
  lin_pass2<<<32, 256, 0, stream>>>(kvt, kzp);
  lin_pass3<<<1024, 256, 0, stream>>>(qkvAS + 3072, kvt, kzp, comb);
  // sum = [attn|ssm] @ [Wp_a;Wo_s] + (bp_a+bo_s): M=8192,N=1024,K=2048 -> sml, grid 256 (lgnmt=6)
  gemm_sml<EPI_STORE, 0><<<256, 512, 0, stream>>>(comb, wTpo, bcomb, sum, nullptr, 2048, 2048, 1024, 6);
  // x1 = x + sum @ Wo + bo (f32 out): M=8192,N=1024,K=1024
  gemm_sml<EPI_RES, 1><<<256, 512, 0, stream>>>(sum, wTo, bo, x1, x, 1024, 1024, 1024, 6);
  ln_kernel<<<8192, 256, 0, stream>>>(x1, gm, bm, h_);
  // MLP1: M=8192,N=4096,K=1024 -> big, 2-D grid
  gemm_big<EPI_GELU, 0><<<dim3(32, 16), 512, 0, stream>>>(h_, wT1, b1m, gbuf, nullptr, 1024, 1024, 4096);
  // MLP2: M=8192,N=1024,K=4096 -> sml, grid 256 (lgnmt=6)
  gemm_sml<EPI_RES, 1><<<256, 512, 0, stream>>>(gbuf, wT2, b2m, out, x1, 4096, 4096, 1024, 6);
}

// Round 10
// 614.719 us; speedup vs baseline: 1.1650x; 1.1650x over previous
//
#include <hip/hip_runtime.h>
#include <hip/hip_bf16.h>
#include <math.h>

typedef __hip_bfloat16 bf16;
typedef float f32x4 __attribute__((ext_vector_type(4)));
typedef short short8 __attribute__((ext_vector_type(8)));
typedef unsigned short u16x4 __attribute__((ext_vector_type(4)));
typedef unsigned short u16x8 __attribute__((ext_vector_type(8)));

#define AS1 __attribute__((address_space(1)))
#define AS3 __attribute__((address_space(3)))

__device__ __forceinline__ void gload16(const void* g, void* l) {
  __builtin_amdgcn_global_load_lds((const AS1 unsigned int*)g, (AS3 unsigned int*)l, 16, 0, 0);
}
__device__ __forceinline__ float b2f(unsigned short u) {
  union { unsigned int i; float f; } c; c.i = ((unsigned int)u) << 16; return c.f;
}
__device__ __forceinline__ unsigned short f2b(float f) {
  bf16 h = __float2bfloat16(f);
  unsigned short s; __builtin_memcpy(&s, &h, 2); return s;
}
__device__ __forceinline__ f32x4 mfma16(short8 a, short8 b, f32x4 c) {
  return __builtin_amdgcn_mfma_f32_16x16x32_bf16(a, b, c, 0, 0, 0);
}

#define BARR asm volatile("s_barrier" ::: "memory")
#define LGKM0 asm volatile("s_waitcnt lgkmcnt(0)" ::: "memory")
#define VM4 asm volatile("s_waitcnt vmcnt(4)" ::: "memory")
#define VM3 asm volatile("s_waitcnt vmcnt(3)" ::: "memory")
#define VM0 asm volatile("s_waitcnt vmcnt(0)" ::: "memory")
#define SB0 __builtin_amdgcn_sched_barrier(0)
#define PRIO1 __builtin_amdgcn_s_setprio(1)
#define PRIO0 __builtin_amdgcn_s_setprio(0)

// ---------------- LayerNorm: f32 in -> bf16 out, one block per 1024-wide row ----------------
__global__ __launch_bounds__(256) void ln_kernel(
    const float* __restrict__ X, const float* __restrict__ G,
    const float* __restrict__ Bb, unsigned short* __restrict__ Y) {
  __shared__ float red[8];
  const size_t row = blockIdx.x;
  const int tid = threadIdx.x;
  f32x4 v = *(const f32x4*)&X[row * 1024 + tid * 4];
  float s = 0.f, sq = 0.f;
#pragma unroll
  for (int j = 0; j < 4; ++j) { s += v[j]; sq += v[j] * v[j]; }
#pragma unroll
  for (int o = 1; o < 64; o <<= 1) { s += __shfl_xor(s, o); sq += __shfl_xor(sq, o); }
  if ((tid & 63) == 0) { red[tid >> 6] = s; red[4 + (tid >> 6)] = sq; }
  __syncthreads();
  s = red[0] + red[1] + red[2] + red[3];
  sq = red[4] + red[5] + red[6] + red[7];
  const float mean = s * (1.f / 1024.f);
  const float var = sq * (1.f / 1024.f) - mean * mean;
  const float inv = 1.f / sqrtf(var + 1e-5f);
  f32x4 gv = *(const f32x4*)&G[tid * 4];
  f32x4 bv = *(const f32x4*)&Bb[tid * 4];
  u16x4 ov;
#pragma unroll
  for (int j = 0; j < 4; ++j) ov[j] = f2b((v[j] - mean) * inv * gv[j] + bv[j]);
  *(u16x4*)&Y[row * 1024 + tid * 4] = ov;
}

// ---------------- Weight transpose: f32 src[K][N] -> bf16 dst[n][dld] (+doff) ----------------
__global__ __launch_bounds__(256) void transpose_w(
    const float* __restrict__ S, unsigned short* __restrict__ D,
    int N, int dld, int doff) {
  __shared__ __attribute__((aligned(16))) unsigned short t[64][72];
  const int k0 = blockIdx.x * 64, n0 = blockIdx.y * 64;
  const int tid = threadIdx.x;
#pragma unroll
  for (int i = 0; i < 2; ++i) {
    int c = i * 256 + tid;
    int row = c >> 3, c8 = c & 7;
    f32x4 a = *(const f32x4*)&S[(size_t)(k0 + row) * N + n0 + c8 * 8];
    f32x4 b = *(const f32x4*)&S[(size_t)(k0 + row) * N + n0 + c8 * 8 + 4];
    u16x8 o;
#pragma unroll
    for (int j = 0; j < 4; ++j) { o[j] = f2b(a[j]); o[4 + j] = f2b(b[j]); }
    *(u16x8*)&t[row][c8 * 8] = o;
  }
  __syncthreads();
#pragma unroll
  for (int i = 0; i < 2; ++i) {
    int c = i * 256 + tid;
    int nrow = c >> 3, k8 = c & 7;
    u16x8 o;
#pragma unroll
    for (int j = 0; j < 8; ++j) o[j] = t[k8 * 8 + j][nrow];
    *(u16x8*)&D[(size_t)(n0 + nrow) * dld + doff + k0 + k8 * 8] = o;
  }
}

__global__ __launch_bounds__(256) void bias_comb(
    const float* __restrict__ a, const float* __restrict__ b, float* __restrict__ o) {
  int i = blockIdx.x * 256 + threadIdx.x;
  o[i] = a[i] + b[i];
}

// concat bias: o[0..2N) = a | b
__global__ __launch_bounds__(256) void bias_cat(
    const float* __restrict__ a, const float* __restrict__ b, float* __restrict__ o, int N) {
  int i = blockIdx.x * 256 + threadIdx.x;
  o[i] = (i < N) ? a[i] : b[i - N];
}

#define EPI_STORE 0
#define EPI_GELU 1
#define EPI_RES 2

// ---------------- GEMM big: 256x256, BK=64, counted-vmcnt, 2 phases/tile x 32 MFMA --------
// R7 exact (best measured: QKV 132 us, MfmaUtil 33%). 8 waves (2M x 4N), per-wave 128x64.
// 128 KB LDS = 2 buf x (A 32KB + B 32KB), frag-major (0 conflicts, ds_read at base+lane*16).
// Per phase: {12 ds_read || stage one kk-group of tile T+1 (4 gload_lds) -> barrier ->
// lgkmcnt(0) -> 32 MFMA -> vmcnt(4) retiring the group staged one phase earlier -> barrier}.
// Invariant (prologue/steady/tail verified): at each phase end exactly one 4-load group is
// outstanding, and it is the group the NEXT phase reads.
// Validated vs alternatives: 2-D grid beats XCD swizzle (R8: FETCH 74->203 MB); LDS-staged B
// beats register-B (R9: +45% dur, compiler vmcnt on critical path).
template <int EPI, int OF32>
__global__ __launch_bounds__(512, 2) void gemm_big(
    const unsigned short* __restrict__ A, const unsigned short* __restrict__ Bt,
    const float* __restrict__ bias, void* __restrict__ Cv,
    const float* __restrict__ res, int K, int ldA, int ldC) {
  __shared__ __attribute__((aligned(16))) unsigned short Abuf[2][2][16 * 512];
  __shared__ __attribute__((aligned(16))) unsigned short Bbuf[2][2][16 * 512];
  const int tid = threadIdx.x, lane = tid & 63, wv = tid >> 6;
  const int g = lane >> 4, r = lane & 15;
  const int wr = wv >> 2, wc = wv & 3;
  const size_t arow0 = (size_t)blockIdx.x * 256;
  const size_t brow0 = (size_t)blockIdx.y * 256;
  const size_t ldAs = (size_t)ldA, Ksz = (size_t)K;
  // frag f covers rows f*16+(l&15), k kk*32+(l>>4)*8; wave wv stages frags {2wv, 2wv+1}
  const unsigned short* gA0 = A + (arow0 + (size_t)((2 * wv + 0) * 16 + r)) * ldAs + g * 8;
  const unsigned short* gA1 = A + (arow0 + (size_t)((2 * wv + 1) * 16 + r)) * ldAs + g * 8;
  const unsigned short* gB0 = Bt + (brow0 + (size_t)((2 * wv + 0) * 16 + r)) * Ksz + g * 8;
  const unsigned short* gB1 = Bt + (brow0 + (size_t)((2 * wv + 1) * 16 + r)) * Ksz + g * 8;
  const int nT = K >> 6;
  f32x4 acc[8][4] = {};
  short8 af[8], bfr[4];

#define STG(BUF, KK, T_) do { size_t o_ = (size_t)(T_) * 64 + (KK) * 32;            \
    gload16(gA0 + o_, &Abuf[BUF][KK][(2 * wv + 0) * 512]);                           \
    gload16(gA1 + o_, &Abuf[BUF][KK][(2 * wv + 1) * 512]);                           \
    gload16(gB0 + o_, &Bbuf[BUF][KK][(2 * wv + 0) * 512]);                           \
    gload16(gB1 + o_, &Bbuf[BUF][KK][(2 * wv + 1) * 512]); } while (0)
#define PHASE(CUR, KK, T_)                                                           \
  do {                                                                               \
    const bool s1_ = (T_) + 1 < nT;                                                  \
    _Pragma("unroll") for (int m_ = 0; m_ < 8; ++m_)                                 \
      af[m_] = *(const short8*)&Abuf[CUR][KK][(wr * 8 + m_) * 512 + lane * 8];       \
    _Pragma("unroll") for (int n_ = 0; n_ < 4; ++n_)                                 \
      bfr[n_] = *(const short8*)&Bbuf[CUR][KK][(wc * 4 + n_) * 512 + lane * 8];      \
    if (s1_) STG(CUR ^ 1, KK, (T_) + 1);                                             \
    BARR; LGKM0; SB0;                                                                \
    PRIO1;                                                                           \
    _Pragma("unroll") for (int m_ = 0; m_ < 8; ++m_)                                 \
      _Pragma("unroll") for (int n_ = 0; n_ < 4; ++n_)                               \
        acc[m_][n_] = mfma16(af[m_], bfr[n_], acc[m_][n_]);                          \
    PRIO0;                                                                           \
    if (s1_) { VM4; } else if ((KK) == 0) { VM0; }                                   \
    BARR; SB0;                                                                       \
  } while (0)

  // prologue: stage tile 0 both kk-groups; retire kk0's group (kk1's 4 stay in flight)
  STG(0, 0, 0); STG(0, 1, 0);
  VM4; BARR; SB0;

  for (int T = 0; T < nT; ++T) {
    const int cur = T & 1;
    PHASE(cur, 0, T);
    PHASE(cur, 1, T);
  }
#undef PHASE
#undef STG

#pragma unroll
  for (int m = 0; m < 8; ++m) {
#pragma unroll
    for (int n = 0; n < 4; ++n) {
      const int col = (int)brow0 + wc * 64 + n * 16 + r;
      const float bv = bias[col];
#pragma unroll
      for (int i = 0; i < 4; ++i) {
        const size_t row = arow0 + wr * 128 + m * 16 + g * 4 + i;
        float v = acc[m][n][i] + bv;
        if (EPI == EPI_GELU) v = 0.5f * v * (1.f + erff(v * 0.70710678118f));
        if (EPI == EPI_RES) v += res[row * ldC + col];
        if (OF32) ((float*)Cv)[row * ldC + col] = v;
        else ((unsigned short*)Cv)[row * ldC + col] = f2b(v);
      }
    }
  }
}

// ---------------- GEMM small: 128x256, BK=64, counted-vmcnt (R7 exact) --------------------
// 8 waves (2M x 4N), per-wave 64x64. 96 KB LDS. 2 phases/tile x 16 MFMA; 3 gloads/phase;
// vmcnt(3) retires the group issued one phase earlier. Validated vs ring-3 BK=32 @2blk/CU
// (R8: ~+6 us net) — this version is the better-measured one.
template <int EPI, int OF32>
__global__ __launch_bounds__(512, 2) void gemm_sml(
    const unsigned short* __restrict__ A, const unsigned short* __restrict__ Bt,
    const float* __restrict__ bias, void* __restrict__ Cv,
    const float* __restrict__ res, int K, int ldA, int ldC) {
  __shared__ __attribute__((aligned(16))) unsigned short Abuf[2][2][8 * 512];
  __shared__ __attribute__((aligned(16))) unsigned short Bbuf[2][2][16 * 512];
  const int tid = threadIdx.x, lane = tid & 63, wv = tid >> 6;
  const int g = lane >> 4, r = lane & 15;
  const int wr = wv >> 2, wc = wv & 3;
  const size_t arow0 = (size_t)blockIdx.x * 128;
  const size_t brow0 = (size_t)blockIdx.y * 256;
  const size_t ldAs = (size_t)ldA, Ksz = (size_t)K;
  const unsigned short* gAs = A + (arow0 + (size_t)(wv * 16 + r)) * ldAs + g * 8;
  const unsigned short* gB0 = Bt + (brow0 + (size_t)((2 * wv + 0) * 16 + r)) * Ksz + g * 8;
  const unsigned short* gB1 = Bt + (brow0 + (size_t)((2 * wv + 1) * 16 + r)) * Ksz + g * 8;
  const int nT = K >> 6;
  f32x4 acc[4][4] = {};
  short8 af[4], bfr[4];

#define STG(BUF, KK, T_) do { size_t o_ = (size_t)(T_) * 64 + (KK) * 32;            \
    gload16(gAs + o_, &Abuf[BUF][KK][wv * 512]);                                     \
    gload16(gB0 + o_, &Bbuf[BUF][KK][(2 * wv + 0) * 512]);                           \
    gload16(gB1 + o_, &Bbuf[BUF][KK][(2 * wv + 1) * 512]); } while (0)
#define RD(CUR, KK) do {                                                             \
    _Pragma("unroll") for (int m_ = 0; m_ < 4; ++m_)                                 \
      af[m_] = *(const short8*)&Abuf[CUR][KK][(wr * 4 + m_) * 512 + lane * 8];       \
    _Pragma("unroll") for (int n_ = 0; n_ < 4; ++n_)                                 \
      bfr[n_] = *(const short8*)&Bbuf[CUR][KK][(wc * 4 + n_) * 512 + lane * 8]; } while (0)
#define MM() _Pragma("unroll") for (int m_ = 0; m_ < 4; ++m_)                        \
    _Pragma("unroll") for (int n_ = 0; n_ < 4; ++n_)                                 \
      acc[m_][n_] = mfma16(af[m_], bfr[n_], acc[m_][n_]);

  STG(0, 0, 0); STG(0, 1, 0);
  VM3; BARR; SB0;

  for (int T = 0; T < nT; ++T) {
    const int cur = T & 1;
    const bool s1 = (T + 1) < nT;
    // p0: kk0 ; stage T+1 kk0 ; end: retire this tile's kk1 group
    RD(cur, 0);
    if (s1) STG(cur ^ 1, 0, T + 1);
    BARR; LGKM0; SB0;
    PRIO1; MM(); PRIO0;
    if (s1) { VM3; } else { VM0; }
    BARR; SB0;
    // p1: kk1 ; stage T+1 kk1 ; end: retire next tile's kk0 group
    RD(cur, 1);
    if (s1) STG(cur ^ 1, 1, T + 1);
    BARR; LGKM0; SB0;
    PRIO1; MM(); PRIO0;
    if (s1) { VM3; }
    BARR; SB0;
  }
#undef STG
#undef RD
#undef MM

#pragma unroll
  for (int m = 0; m < 4; ++m) {
#pragma unroll
    for (int n = 0; n < 4; ++n) {
      const int col = (int)brow0 + wc * 64 + n * 16 + r;
      const float bv = bias[col];
#pragma unroll
      for (int i = 0; i < 4; ++i) {
        const size_t row = arow0 + wr * 64 + m * 16 + g * 4 + i;
        float v = acc[m][n][i] + bv;
        if (EPI == EPI_GELU) v = 0.5f * v * (1.f + erff(v * 0.70710678118f));
        if (EPI == EPI_RES) v += res[row * ldC + col];
        if (OF32) ((float*)Cv)[row * ldC + col] = v;
        else ((unsigned short*)Cv)[row * ldC + col] = f2b(v);
      }
    }
  }
}

// ---------------- Sliding-window attention: one wg per (b,h,qblock of 128) ----------------
// qkv layout: [8192][6144] bf16 (fused QKV buffer, attention half at cols 0..3071):
// q = cols 0..1023, k = 1024..2047, v = 2048..3071, head h at h*64.
__global__ __launch_bounds__(256) void swa_kernel(
    const unsigned short* __restrict__ qkv, unsigned short* __restrict__ outc) {
  __shared__ __attribute__((aligned(16))) unsigned short Ks[256 * 64];   // swizzled [s][e]
  __shared__ __attribute__((aligned(16))) unsigned short Vt[64 * 264];   // [e][s]
  __shared__ __attribute__((aligned(16))) unsigned short Ps[128 * 264];  // [r][s]
  __shared__ __attribute__((aligned(16))) float dn[128];
  const int bid = blockIdx.x;
  const int qb = bid & 31, h = (bid >> 5) & 15, b = bid >> 9;
  const long btok = (long)b * 4096;
  const long tok0 = btok + (long)qb * 128;
  const int tid = threadIdx.x, lane = tid & 63, wv = tid >> 6;
  const int g = lane >> 4, r = lane & 15;

#pragma unroll
  for (int i = 0; i < 8; ++i) {  // K stage: 16B chunks, chunk-XOR swizzle over 8 chunks/row
    int chunk = (wv * 8 + i) * 64 + lane;
    int s = chunk >> 3, cc = (chunk & 7) ^ (s & 7);
    long kt = tok0 - 128 + s; if (kt < btok) kt = btok;  // block 0: masked anyway
    gload16(&qkv[(size_t)kt * 6144 + 1024 + h * 64 + cc * 8], &Ks[(wv * 8 + i) * 512]);
  }
#pragma unroll
  for (int i = 0; i < 8; ++i) {  // V transposed stage
    int chunk = i * 256 + tid;
    int s = chunk >> 3, e8 = chunk & 7;
    long kt = tok0 - 128 + s; if (kt < btok) kt = btok;
    u16x8 u = *(const u16x8*)&qkv[(size_t)kt * 6144 + 2048 + h * 64 + e8 * 8];
#pragma unroll
    for (int j = 0; j < 8; ++j) Vt[(e8 * 8 + j) * 264 + s] = u[j];
  }
  short8 qf[2][2];  // Q frags direct from global
#pragma unroll
  for (int m = 0; m < 2; ++m)
#pragma unroll
    for (int kc = 0; kc < 2; ++kc)
      qf[m][kc] = *(const short8*)&qkv[(size_t)(tok0 + wv * 32 + m * 16 + r) * 6144 + h * 64 + kc * 32 + g * 8];
  __syncthreads();

  float rs[2][4] = {};
  for (int n = 0; n < 16; ++n) {
    const int srow = n * 16 + r;
    short8 kf0 = *(const short8*)&Ks[srow * 64 + ((g) ^ (srow & 7)) * 8];
    short8 kf1 = *(const short8*)&Ks[srow * 64 + ((4 + g) ^ (srow & 7)) * 8];
#pragma unroll
    for (int m = 0; m < 2; ++m) {
      f32x4 acc = {0.f, 0.f, 0.f, 0.f};
      acc = mfma16(qf[m][0], kf0, acc);
      acc = mfma16(qf[m][1], kf1, acc);
#pragma unroll
      for (int i = 0; i < 4; ++i) {
        int rr = wv * 32 + m * 16 + g * 4 + i;
        int ss = n * 16 + r;
        bool valid = (ss >= rr + 1) && (ss <= rr + 128) && (qb > 0 || ss >= 128);
        float p = valid ? __expf(acc[i] * 0.125f) : 0.f;  // scores small: no max-sub needed
        rs[m][i] += p;
        Ps[rr * 264 + ss] = f2b(p);
      }
    }
  }
#pragma unroll
  for (int m = 0; m < 2; ++m)
#pragma unroll
    for (int i = 0; i < 4; ++i) {
      float v = rs[m][i];
      v += __shfl_xor(v, 1); v += __shfl_xor(v, 2);
      v += __shfl_xor(v, 4); v += __shfl_xor(v, 8);
      if (r == i) dn[wv * 32 + m * 16 + g * 4 + i] = v;
    }
  __syncthreads();

  f32x4 oacc[2][4] = {};
  for (int sc = 0; sc < 8; ++sc) {
    short8 pf[2], vf[4];
#pragma unroll
    for (int m = 0; m < 2; ++m)
      pf[m] = *(const short8*)&Ps[(wv * 32 + m * 16 + r) * 264 + sc * 32 + g * 8];
#pragma unroll
    for (int n = 0; n < 4; ++n)
      vf[n] = *(const short8*)&Vt[(n * 16 + r) * 264 + sc * 32 + g * 8];
#pragma unroll
    for (int m = 0; m < 2; ++m)
#pragma unroll
      for (int n = 0; n < 4; ++n)
        oacc[m][n] = mfma16(pf[m], vf[n], oacc[m][n]);
  }
#pragma unroll
  for (int m = 0; m < 2; ++m) {
    f32x4 dv = *(const f32x4*)&dn[wv * 32 + m * 16 + g * 4];
#pragma unroll
    for (int n = 0; n < 4; ++n) {
      int col = h * 64 + n * 16 + r;
#pragma unroll
      for (int i = 0; i < 4; ++i) {
        size_t row = (size_t)(tok0 + wv * 32 + m * 16 + g * 4 + i);
        outc[row * 2048 + col] = f2b(oacc[m][n][i] / dv[i]);
      }
    }
  }
}

// ---------------- Linear attention pass 1: per-chunk KVt[f][e], kz[e] ----------------
// qkv points at the S-half (fused buffer + 3072), row stride 6144.
__global__ __launch_bounds__(256) void lin_pass1(
    const unsigned short* __restrict__ qkv, float* __restrict__ KVt, float* __restrict__ kz) {
  __shared__ __attribute__((aligned(16))) unsigned short kf[128 * 72];
  __shared__ __attribute__((aligned(16))) unsigned short vs[128 * 72];
  const int bid = blockIdx.x;
  const int ch = bid & 31, h = (bid >> 5) & 15, b = bid >> 9;
  const size_t tok0 = (size_t)b * 4096 + (size_t)ch * 128;
  const int tid = threadIdx.x;
#pragma unroll
  for (int i = 0; i < 4; ++i) {
    int c = i * 256 + tid;
    int row = c >> 3, e8 = c & 7;
    u16x8 uk = *(const u16x8*)&qkv[(tok0 + row) * 6144 + 1024 + h * 64 + e8 * 8];
    u16x8 uv = *(const u16x8*)&qkv[(tok0 + row) * 6144 + 2048 + h * 64 + e8 * 8];
    u16x8 tk;
#pragma unroll
    for (int j = 0; j < 8; ++j) {
      float x = b2f(uk[j]);
      x = (x > 0.f) ? x : expm1f(x);  // elu
      tk[j] = f2b(x + 1.0001f);
    }
    *(u16x8*)&kf[row * 72 + e8 * 8] = tk;
    *(u16x8*)&vs[row * 72 + e8 * 8] = uv;
  }
  __syncthreads();
  const int e0 = (tid & 15) * 4, f0 = (tid >> 4) * 4;
  float acc[4][4] = {};
  for (int c = 0; c < 128; ++c) {
    u16x4 ku = *(const u16x4*)&kf[c * 72 + e0];
    u16x4 vu = *(const u16x4*)&vs[c * 72 + f0];
    float ke[4], vv[4];
#pragma unroll
    for (int j = 0; j < 4; ++j) { ke[j] = b2f(ku[j]); vv[j] = b2f(vu[j]); }
#pragma unroll
    for (int jf = 0; jf < 4; ++jf)
#pragma unroll
      for (int je = 0; je < 4; ++je)
        acc[jf][je] += vv[jf] * ke[je];
  }
  const size_t base = (size_t)bid * 4096;
#pragma unroll
  for (int jf = 0; jf < 4; ++jf) {
    f32x4 o = {acc[jf][0], acc[jf][1], acc[jf][2], acc[jf][3]};
    *(f32x4*)&KVt[base + (f0 + jf) * 64 + e0] = o;
  }
  if (tid < 64) {
    float s = 0.f;
    for (int c = 0; c < 128; ++c) s += b2f(kf[c * 72 + tid]);
    kz[(size_t)bid * 64 + tid] = s;
  }
}

// ---------------- pass 2: per (b,h) exclusive prefix over 32 chunks (in place) ----------------
__global__ __launch_bounds__(256) void lin_pass2(float* __restrict__ KVt, float* __restrict__ kz) {
  const int bh = blockIdx.x;
  const int tid = threadIdx.x;
  f32x4 run[4] = {};
  for (int ch = 0; ch < 32; ++ch) {
    const size_t base = ((size_t)bh * 32 + ch) * 4096;
#pragma unroll
    for (int i = 0; i < 4; ++i) {
      float* p = &KVt[base + (size_t)(i * 256 + tid) * 4];
      f32x4 c = *(f32x4*)p;
      *(f32x4*)p = run[i];
      run[i] += c;
    }
  }
  if (tid < 64) {
    float rz = 0.f;
    for (int ch = 0; ch < 32; ++ch) {
      float* p = &kz[((size_t)bh * 32 + ch) * 64 + tid];
      float c = *p; *p = rz; rz += c;
    }
  }
}

// ---------------- pass 3: o = (q@S_prev + tril(qk^T)@v) / (q.z_prev + rowsumA + 1e-6) ----------------
__global__ __launch_bounds__(256) void lin_pass3(
    const unsigned short* __restrict__ qkv, const float* __restrict__ KVt,
    const float* __restrict__ kz, unsigned short* __restrict__ outc) {
  __shared__ __attribute__((aligned(16))) unsigned short qf[128 * 72];
  __shared__ __attribute__((aligned(16))) unsigned short kf[128 * 72];
  __shared__ __attribute__((aligned(16))) unsigned short vt[64 * 136];
  __shared__ __attribute__((aligned(16))) unsigned short st[64 * 72];
  __shared__ __attribute__((aligned(16))) unsigned short am[128 * 136];
  __shared__ __attribute__((aligned(16))) float zs[64];
  __shared__ __attribute__((aligned(16))) float dnl[128];
  const int bid = blockIdx.x;
  const int ch = bid & 31, h = (bid >> 5) & 15, b = bid >> 9;
  const size_t tok0 = (size_t)b * 4096 + (size_t)ch * 128;
  const int tid = threadIdx.x, lane = tid & 63, wv = tid >> 6;
  const int g = lane >> 4, r = lane & 15;

#pragma unroll
  for (int i = 0; i < 4; ++i) {
    int c = i * 256 + tid;
    int row = c >> 3, e8 = c & 7;
    u16x8 uq = *(const u16x8*)&qkv[(tok0 + row) * 6144 + h * 64 + e8 * 8];
    u16x8 uk = *(const u16x8*)&qkv[(tok0 + row) * 6144 + 1024 + h * 64 + e8 * 8];
    u16x8 uv = *(const u16x8*)&qkv[(tok0 + row) * 6144 + 2048 + h * 64 + e8 * 8];
    u16x8 tq, tk;
#pragma unroll
    for (int j = 0; j < 8; ++j) {
      float x = b2f(uq[j]) * 0.125f;
      x = (x > 0.f) ? x : expm1f(x);
      tq[j] = f2b(x + 1.0001f);
      float y = b2f(uk[j]);
      y = (y > 0.f) ? y : expm1f(y);
      tk[j] = f2b(y + 1.0001f);
    }
    *(u16x8*)&qf[row * 72 + e8 * 8] = tq;
    *(u16x8*)&kf[row * 72 + e8 * 8] = tk;
#pragma unroll
    for (int j = 0; j < 8; ++j) vt[(e8 * 8 + j) * 136 + row] = uv[j];
  }
#pragma unroll
  for (int i = 0; i < 2; ++i) {  // S_prev^T (f-major) f32 -> bf16 LDS
    int idx = i * 256 + tid;
    int f = idx >> 3, e8 = idx & 7;
    f32x4 s0 = *(const f32x4*)&KVt[(size_t)bid * 4096 + f * 64 + e8 * 8];
    f32x4 s1 = *(const f32x4*)&KVt[(size_t)bid * 4096 + f * 64 + e8 * 8 + 4];
    u16x8 t;
#pragma unroll
    for (int j = 0; j < 4; ++j) { t[j] = f2b(s0[j]); t[4 + j] = f2b(s1[j]); }
    *(u16x8*)&st[f * 72 + e8 * 8] = t;
  }
  if (tid < 64) zs[tid] = kz[(size_t)bid * 64 + tid];
  __syncthreads();

  short8 aq[2][2];
#pragma unroll
  for (int m = 0; m < 2; ++m)
#pragma unroll
    for (int kc = 0; kc < 2; ++kc)
      aq[m][kc] = *(const short8*)&qf[(wv * 32 + m * 16 + r) * 72 + kc * 32 + g * 8];

  float rsA[2][4] = {};
  for (int n = 0; n < 8; ++n) {  // A = tril(qf @ kf^T), bf16 to LDS + rowsums
    short8 bk0 = *(const short8*)&kf[(n * 16 + r) * 72 + g * 8];
    short8 bk1 = *(const short8*)&kf[(n * 16 + r) * 72 + 32 + g * 8];
#pragma unroll
    for (int m = 0; m < 2; ++m) {
      f32x4 acc = {0.f, 0.f, 0.f, 0.f};
      acc = mfma16(aq[m][0], bk0, acc);
      acc = mfma16(aq[m][1], bk1, acc);
#pragma unroll
      for (int i = 0; i < 4; ++i) {
        int rr = wv * 32 + m * 16 + g * 4 + i;
        int cc = n * 16 + r;
        float v = (cc <= rr) ? acc[i] : 0.f;
        rsA[m][i] += v;
        am[rr * 136 + cc] = f2b(v);
      }
    }
  }
#pragma unroll
  for (int m = 0; m < 2; ++m)
#pragma unroll
    for (int i = 0; i < 4; ++i) {
      float v = rsA[m][i];
      v += __shfl_xor(v, 1); v += __shfl_xor(v, 2);
      v += __shfl_xor(v, 4); v += __shfl_xor(v, 8);
      if (r == i) dnl[wv * 32 + m * 16 + g * 4 + i] = v;
    }
  __syncthreads();

  if (tid < 128) {  // den = rowsumA + qf . z_prev
    float s = dnl[tid];
#pragma unroll
    for (int e = 0; e < 64; e += 4) {
      u16x4 qv = *(const u16x4*)&qf[tid * 72 + e];
      s += b2f(qv[0]) * zs[e] + b2f(qv[1]) * zs[e + 1] + b2f(qv[2]) * zs[e + 2] + b2f(qv[3]) * zs[e + 3];
    }
    dnl[tid] = s + 1e-6f;
  }

  f32x4 oac[2][4] = {};
#pragma unroll
  for (int kc = 0; kc < 2; ++kc) {  // num += qf @ S_prev
    short8 sf[4];
#pragma unroll
    for (int n = 0; n < 4; ++n) sf[n] = *(const short8*)&st[(n * 16 + r) * 72 + kc * 32 + g * 8];
#pragma unroll
    for (int m = 0; m < 2; ++m)
#pragma unroll
      for (int n = 0; n < 4; ++n)
        oac[m][n] = mfma16(aq[m][kc], sf[n], oac[m][n]);
  }
  for (int c4 = 0; c4 < 4; ++c4) {  // num += A @ v
    short8 pa[2], vb[4];
#pragma unroll
    for (int m = 0; m < 2; ++m)
      pa[m] = *(const short8*)&am[(wv * 32 + m * 16 + r) * 136 + c4 * 32 + g * 8];
#pragma unroll
    for (int n = 0; n < 4; ++n)
      vb[n] = *(const short8*)&vt[(n * 16 + r) * 136 + c4 * 32 + g * 8];
#pragma unroll
    for (int m = 0; m < 2; ++m)
#pragma unroll
      for (int n = 0; n < 4; ++n)
        oac[m][n] = mfma16(pa[m], vb[n], oac[m][n]);
  }
  __syncthreads();
#pragma unroll
  for (int m = 0; m < 2; ++m) {
    f32x4 dv = *(const f32x4*)&dnl[wv * 32 + m * 16 + g * 4];
#pragma unroll
    for (int n = 0; n < 4; ++n) {
      int col = 1024 + h * 64 + n * 16 + r;
#pragma unroll
      for (int i = 0; i < 4; ++i) {
        size_t row = tok0 + wv * 32 + m * 16 + g * 4 + i;
        outc[row * 2048 + col] = f2b(oac[m][n][i] / dv[i]);
      }
    }
  }
}

// ---------------- host ----------------
extern "C" void kernel_launch(void* const* d_in, const int* in_sizes, int n_in,
                              void* d_out, int out_size, void* d_ws, size_t ws_size,
                              hipStream_t stream) {
  (void)in_sizes; (void)n_in; (void)out_size; (void)ws_size;
  const float* x      = (const float*)d_in[0];
  const float* g1     = (const float*)d_in[1];
  const float* b1     = (const float*)d_in[2];
  const float* Wqkv_a = (const float*)d_in[3];
  const float* bqkv_a = (const float*)d_in[4];
  const float* Wp_a   = (const float*)d_in[5];
  const float* bp_a   = (const float*)d_in[6];
  const float* Wqkv_s = (const float*)d_in[7];
  const float* bqkv_s = (const float*)d_in[8];
  const float* Wo_s   = (const float*)d_in[9];
  const float* bo_s   = (const float*)d_in[10];
  const float* Wo     = (const float*)d_in[11];
  const float* bo     = (const float*)d_in[12];
  const float* gm     = (const float*)d_in[13];
  const float* bm     = (const float*)d_in[14];
  const float* W1     = (const float*)d_in[15];
  const float* b1m    = (const float*)d_in[16];
  const float* W2     = (const float*)d_in[17];
  const float* b2m    = (const float*)d_in[18];
  float* out = (float*)d_out;

  char* ws = (char*)d_ws;
  size_t off = 0;
  auto alloc = [&](size_t bytes) { char* p = ws + off; off += (bytes + 255) & ~(size_t)255; return p; };
  unsigned short* wTaS  = (unsigned short*)alloc((size_t)6144 * 1024 * 2);  // [Wqkv_a^T ; Wqkv_s^T]
  unsigned short* wTpo  = (unsigned short*)alloc((size_t)1024 * 2048 * 2);
  unsigned short* wTo   = (unsigned short*)alloc((size_t)1024 * 1024 * 2);
  unsigned short* wT1   = (unsigned short*)alloc((size_t)4096 * 1024 * 2);
  unsigned short* wT2   = (unsigned short*)alloc((size_t)1024 * 4096 * 2);
  float*          bcomb = (float*)alloc(1024 * 4);
  float*          bcat  = (float*)alloc(6144 * 4);
  unsigned short* xn    = (unsigned short*)alloc((size_t)8192 * 1024 * 2);  // reused as h
  unsigned short* qkvAS = (unsigned short*)alloc((size_t)8192 * 6144 * 2);  // fused; reused as gbuf
  unsigned short* comb  = (unsigned short*)alloc((size_t)8192 * 2048 * 2);  // reused as x1 (f32)
  float*          kvt   = (float*)alloc((size_t)1024 * 4096 * 4);           // reused as sum (bf16)
  float*          kzp   = (float*)alloc((size_t)1024 * 64 * 4);
  unsigned short* gbuf  = qkvAS;
  unsigned short* sum   = (unsigned short*)kvt;
  unsigned short* h_    = xn;
  float*          x1    = (float*)comb;  // comb dead once sum is computed

  transpose_w<<<dim3(16, 48), 256, 0, stream>>>(Wqkv_a, wTaS, 3072, 1024, 0);
  transpose_w<<<dim3(16, 48), 256, 0, stream>>>(Wqkv_s, wTaS + (size_t)3072 * 1024, 3072, 1024, 0);
  transpose_w<<<dim3(16, 16), 256, 0, stream>>>(Wp_a, wTpo, 1024, 2048, 0);
  transpose_w<<<dim3(16, 16), 256, 0, stream>>>(Wo_s, wTpo, 1024, 2048, 1024);
  transpose_w<<<dim3(16, 16), 256, 0, stream>>>(Wo, wTo, 1024, 1024, 0);
  transpose_w<<<dim3(16, 64), 256, 0, stream>>>(W1, wT1, 4096, 1024, 0);
  transpose_w<<<dim3(64, 16), 256, 0, stream>>>(W2, wT2, 1024, 4096, 0);
  bias_comb<<<4, 256, 0, stream>>>(bp_a, bo_s, bcomb);
  bias_cat<<<24, 256, 0, stream>>>(bqkv_a, bqkv_s, bcat, 3072);

  ln_kernel<<<8192, 256, 0, stream>>>(x, g1, b1, xn);
  // fused QKV: M=8192, N=6144, K=1024 -> big 256x256, grid 32x24
  gemm_big<EPI_STORE, 0><<<dim3(32, 24), 512, 0, stream>>>(xn, wTaS, bcat, qkvAS, nullptr, 1024, 1024, 6144);
  swa_kernel<<<1024, 256, 0, stream>>>(qkvAS, comb);
  lin_pass1<<<1024, 256, 0, stream>>>(qkvAS + 3072, kvt, kzp);
  lin_pass2<<<32, 256, 0, stream>>>(kvt, kzp);
  lin_pass3<<<1024, 256, 0, stream>>>(qkvAS + 3072, kvt, kzp, comb);
  // sum = [attn|ssm] @ [Wp_a;Wo_s] + (bp_a+bo_s): M=8192,N=1024,K=2048 -> small, grid 64x4
  gemm_sml<EPI_STORE, 0><<<dim3(64, 4), 512, 0, stream>>>(comb, wTpo, bcomb, sum, nullptr, 2048, 2048, 1024);
  // x1 = x + sum @ Wo + bo (f32 out): M=8192,N=1024,K=1024
  gemm_sml<EPI_RES, 1><<<dim3(64, 4), 512, 0, stream>>>(sum, wTo, bo, x1, x, 1024, 1024, 1024);
  ln_kernel<<<8192, 256, 0, stream>>>(x1, gm, bm, h_);
  // MLP1: M=8192,N=4096,K=1024 -> big, grid 32x16
  gemm_big<EPI_GELU, 0><<<dim3(32, 16), 512, 0, stream>>>(h_, wT1, b1m, gbuf, nullptr, 1024, 1024, 4096);
  // MLP2: M=8192,N=1024,K=4096 -> small, grid 64x4
  gemm_sml<EPI_RES, 1><<<dim3(64, 4), 512, 0, stream>>>(gbuf, wT2, b2m, out, x1, 4096, 4096, 1024);
}

// Round 11
// 612.512 us; speedup vs baseline: 1.1692x; 1.0036x over previous
//
#include <hip/hip_runtime.h>
#include <hip/hip_bf16.h>
#include <math.h>

typedef __hip_bfloat16 bf16;
typedef float f32x4 __attribute__((ext_vector_type(4)));
typedef short short8 __attribute__((ext_vector_type(8)));
typedef unsigned short u16x4 __attribute__((ext_vector_type(4)));
typedef unsigned short u16x8 __attribute__((ext_vector_type(8)));

#define AS1 __attribute__((address_space(1)))
#define AS3 __attribute__((address_space(3)))

__device__ __forceinline__ void gload16(const void* g, void* l) {
  __builtin_amdgcn_global_load_lds((const AS1 unsigned int*)g, (AS3 unsigned int*)l, 16, 0, 0);
}
__device__ __forceinline__ float b2f(unsigned short u) {
  union { unsigned int i; float f; } c; c.i = ((unsigned int)u) << 16; return c.f;
}
__device__ __forceinline__ unsigned short f2b(float f) {
  bf16 h = __float2bfloat16(f);
  unsigned short s; __builtin_memcpy(&s, &h, 2); return s;
}
__device__ __forceinline__ f32x4 mfma16(short8 a, short8 b, f32x4 c) {
  return __builtin_amdgcn_mfma_f32_16x16x32_bf16(a, b, c, 0, 0, 0);
}

#define BARR asm volatile("s_barrier" ::: "memory")
#define LGKM0 asm volatile("s_waitcnt lgkmcnt(0)" ::: "memory")
#define VM8 asm volatile("s_waitcnt vmcnt(8)" ::: "memory")
#define VM6 asm volatile("s_waitcnt vmcnt(6)" ::: "memory")
#define VM4 asm volatile("s_waitcnt vmcnt(4)" ::: "memory")
#define VM3 asm volatile("s_waitcnt vmcnt(3)" ::: "memory")
#define VM0 asm volatile("s_waitcnt vmcnt(0)" ::: "memory")
#define SB0 __builtin_amdgcn_sched_barrier(0)
#define PRIO1 __builtin_amdgcn_s_setprio(1)
#define PRIO0 __builtin_amdgcn_s_setprio(0)

// ---------------- LayerNorm: f32 in -> bf16 out, one block per 1024-wide row ----------------
__global__ __launch_bounds__(256) void ln_kernel(
    const float* __restrict__ X, const float* __restrict__ G,
    const float* __restrict__ Bb, unsigned short* __restrict__ Y) {
  __shared__ float red[8];
  const size_t row = blockIdx.x;
  const int tid = threadIdx.x;
  f32x4 v = *(const f32x4*)&X[row * 1024 + tid * 4];
  float s = 0.f, sq = 0.f;
#pragma unroll
  for (int j = 0; j < 4; ++j) { s += v[j]; sq += v[j] * v[j]; }
#pragma unroll
  for (int o = 1; o < 64; o <<= 1) { s += __shfl_xor(s, o); sq += __shfl_xor(sq, o); }
  if ((tid & 63) == 0) { red[tid >> 6] = s; red[4 + (tid >> 6)] = sq; }
  __syncthreads();
  s = red[0] + red[1] + red[2] + red[3];
  sq = red[4] + red[5] + red[6] + red[7];
  const float mean = s * (1.f / 1024.f);
  const float var = sq * (1.f / 1024.f) - mean * mean;
  const float inv = 1.f / sqrtf(var + 1e-5f);
  f32x4 gv = *(const f32x4*)&G[tid * 4];
  f32x4 bv = *(const f32x4*)&Bb[tid * 4];
  u16x4 ov;
#pragma unroll
  for (int j = 0; j < 4; ++j) ov[j] = f2b((v[j] - mean) * inv * gv[j] + bv[j]);
  *(u16x4*)&Y[row * 1024 + tid * 4] = ov;
}

// ---------------- Weight transpose: f32 src[K][N] -> bf16 dst[n][dld] (+doff) ----------------
__global__ __launch_bounds__(256) void transpose_w(
    const float* __restrict__ S, unsigned short* __restrict__ D,
    int N, int dld, int doff) {
  __shared__ __attribute__((aligned(16))) unsigned short t[64][72];
  const int k0 = blockIdx.x * 64, n0 = blockIdx.y * 64;
  const int tid = threadIdx.x;
#pragma unroll
  for (int i = 0; i < 2; ++i) {
    int c = i * 256 + tid;
    int row = c >> 3, c8 = c & 7;
    f32x4 a = *(const f32x4*)&S[(size_t)(k0 + row) * N + n0 + c8 * 8];
    f32x4 b = *(const f32x4*)&S[(size_t)(k0 + row) * N + n0 + c8 * 8 + 4];
    u16x8 o;
#pragma unroll
    for (int j = 0; j < 4; ++j) { o[j] = f2b(a[j]); o[4 + j] = f2b(b[j]); }
    *(u16x8*)&t[row][c8 * 8] = o;
  }
  __syncthreads();
#pragma unroll
  for (int i = 0; i < 2; ++i) {
    int c = i * 256 + tid;
    int nrow = c >> 3, k8 = c & 7;
    u16x8 o;
#pragma unroll
    for (int j = 0; j < 8; ++j) o[j] = t[k8 * 8 + j][nrow];
    *(u16x8*)&D[(size_t)(n0 + nrow) * dld + doff + k0 + k8 * 8] = o;
  }
}

__global__ __launch_bounds__(256) void bias_comb(
    const float* __restrict__ a, const float* __restrict__ b, float* __restrict__ o) {
  int i = blockIdx.x * 256 + threadIdx.x;
  o[i] = a[i] + b[i];
}

// concat bias: o[0..2N) = a | b
__global__ __launch_bounds__(256) void bias_cat(
    const float* __restrict__ a, const float* __restrict__ b, float* __restrict__ o, int N) {
  int i = blockIdx.x * 256 + threadIdx.x;
  o[i] = (i < N) ? a[i] : b[i - N];
}

#define EPI_STORE 0
#define EPI_GELU 1
#define EPI_RES 2

// ---------------- GEMM big: 256x256, BK=64, DEEP counted-vmcnt (lead-3), 2x32 MFMA --------
// R7 structure with prefetch lead extended 1 -> 3 phases (m201's depth). Groups G_j (j=2T+kk,
// 4 gload_lds each) live in the existing ring-4 slots [buf][kk]. Phase j: ds_read G_j, stage
// G_{j+3}; phase-end wait retires exactly G_{j+1} (read next phase), leaving G_{j+2},G_{j+3}
// in flight (VM8 steady; VM4/VM0 tail). Slot of G_{j+3} was last ds_read in phase j-1, two
// s_barriers before the overwrite -> race-free. Waits now retire loads issued ~3 phases ago
// (full latency cover) instead of 1. K-order unchanged -> numerics identical.
template <int EPI, int OF32>
__global__ __launch_bounds__(512, 2) void gemm_big(
    const unsigned short* __restrict__ A, const unsigned short* __restrict__ Bt,
    const float* __restrict__ bias, void* __restrict__ Cv,
    const float* __restrict__ res, int K, int ldA, int ldC) {
  __shared__ __attribute__((aligned(16))) unsigned short Abuf[2][2][16 * 512];
  __shared__ __attribute__((aligned(16))) unsigned short Bbuf[2][2][16 * 512];
  const int tid = threadIdx.x, lane = tid & 63, wv = tid >> 6;
  const int g = lane >> 4, r = lane & 15;
  const int wr = wv >> 2, wc = wv & 3;
  const size_t arow0 = (size_t)blockIdx.x * 256;
  const size_t brow0 = (size_t)blockIdx.y * 256;
  const size_t ldAs = (size_t)ldA, Ksz = (size_t)K;
  // frag f covers rows f*16+(l&15), k kk*32+(l>>4)*8; wave wv stages frags {2wv, 2wv+1}
  const unsigned short* gA0 = A + (arow0 + (size_t)((2 * wv + 0) * 16 + r)) * ldAs + g * 8;
  const unsigned short* gA1 = A + (arow0 + (size_t)((2 * wv + 1) * 16 + r)) * ldAs + g * 8;
  const unsigned short* gB0 = Bt + (brow0 + (size_t)((2 * wv + 0) * 16 + r)) * Ksz + g * 8;
  const unsigned short* gB1 = Bt + (brow0 + (size_t)((2 * wv + 1) * 16 + r)) * Ksz + g * 8;
  const int nT = K >> 6;  // >= 16 at all call sites
  f32x4 acc[8][4] = {};
  short8 af[8], bfr[4];

#define STG(BUF, KK, T_) do { size_t o_ = (size_t)(T_) * 64 + (KK) * 32;            \
    gload16(gA0 + o_, &Abuf[BUF][KK][(2 * wv + 0) * 512]);                           \
    gload16(gA1 + o_, &Abuf[BUF][KK][(2 * wv + 1) * 512]);                           \
    gload16(gB0 + o_, &Bbuf[BUF][KK][(2 * wv + 0) * 512]);                           \
    gload16(gB1 + o_, &Bbuf[BUF][KK][(2 * wv + 1) * 512]); } while (0)
#define RDF(CUR, KK) do {                                                            \
    _Pragma("unroll") for (int m_ = 0; m_ < 8; ++m_)                                 \
      af[m_] = *(const short8*)&Abuf[CUR][KK][(wr * 8 + m_) * 512 + lane * 8];       \
    _Pragma("unroll") for (int n_ = 0; n_ < 4; ++n_)                                 \
      bfr[n_] = *(const short8*)&Bbuf[CUR][KK][(wc * 4 + n_) * 512 + lane * 8]; } while (0)
#define MMQ() _Pragma("unroll") for (int m_ = 0; m_ < 8; ++m_)                       \
    _Pragma("unroll") for (int n_ = 0; n_ < 4; ++n_)                                 \
      acc[m_][n_] = mfma16(af[m_], bfr[n_], acc[m_][n_]);

  // prologue: stage G0=(0,k0), G1=(0,k1), G2=(1,k0); VM8 retires G0, leaves G1,G2 (8)
  STG(0, 0, 0); STG(0, 1, 0); STG(1, 0, 1);
  VM8; BARR; SB0;

  for (int T = 0; T < nT; ++T) {
    const int cur = T & 1;
    // phase (T,0): read [cur][0]; stage (T+1,kk1) -> [cur^1][1]
    RDF(cur, 0);
    if (T + 1 < nT) STG(cur ^ 1, 1, T + 1);
    BARR; LGKM0; SB0;
    PRIO1; MMQ(); PRIO0;
    if (T + 1 < nT) { VM8; } else { VM0; }
    BARR; SB0;
    // phase (T,1): read [cur][1]; stage (T+2,kk0) -> [cur][0]
    RDF(cur, 1);
    if (T + 2 < nT) STG(cur, 0, T + 2);
    BARR; LGKM0; SB0;
    PRIO1; MMQ(); PRIO0;
    if (T + 2 < nT) { VM8; } else if (T + 1 < nT) { VM4; }
    BARR; SB0;
  }
#undef STG
#undef RDF
#undef MMQ

#pragma unroll
  for (int m = 0; m < 8; ++m) {
#pragma unroll
    for (int n = 0; n < 4; ++n) {
      const int col = (int)brow0 + wc * 64 + n * 16 + r;
      const float bv = bias[col];
#pragma unroll
      for (int i = 0; i < 4; ++i) {
        const size_t row = arow0 + wr * 128 + m * 16 + g * 4 + i;
        float v = acc[m][n][i] + bv;
        if (EPI == EPI_GELU) v = 0.5f * v * (1.f + erff(v * 0.70710678118f));
        if (EPI == EPI_RES) v += res[row * ldC + col];
        if (OF32) ((float*)Cv)[row * ldC + col] = v;
        else ((unsigned short*)Cv)[row * ldC + col] = f2b(v);
      }
    }
  }
}

// ---------------- GEMM small: 128x256, BK=64, DEEP counted-vmcnt (lead-3) -----------------
// Same deepening: groups of 3 loads; steady VM6 retires G_{j+1}; tail VM3/VM0.
template <int EPI, int OF32>
__global__ __launch_bounds__(512, 2) void gemm_sml(
    const unsigned short* __restrict__ A, const unsigned short* __restrict__ Bt,
    const float* __restrict__ bias, void* __restrict__ Cv,
    const float* __restrict__ res, int K, int ldA, int ldC) {
  __shared__ __attribute__((aligned(16))) unsigned short Abuf[2][2][8 * 512];
  __shared__ __attribute__((aligned(16))) unsigned short Bbuf[2][2][16 * 512];
  const int tid = threadIdx.x, lane = tid & 63, wv = tid >> 6;
  const int g = lane >> 4, r = lane & 15;
  const int wr = wv >> 2, wc = wv & 3;
  const size_t arow0 = (size_t)blockIdx.x * 128;
  const size_t brow0 = (size_t)blockIdx.y * 256;
  const size_t ldAs = (size_t)ldA, Ksz = (size_t)K;
  const unsigned short* gAs = A + (arow0 + (size_t)(wv * 16 + r)) * ldAs + g * 8;
  const unsigned short* gB0 = Bt + (brow0 + (size_t)((2 * wv + 0) * 16 + r)) * Ksz + g * 8;
  const unsigned short* gB1 = Bt + (brow0 + (size_t)((2 * wv + 1) * 16 + r)) * Ksz + g * 8;
  const int nT = K >> 6;  // >= 16 at all call sites
  f32x4 acc[4][4] = {};
  short8 af[4], bfr[4];

#define STG(BUF, KK, T_) do { size_t o_ = (size_t)(T_) * 64 + (KK) * 32;            \
    gload16(gAs + o_, &Abuf[BUF][KK][wv * 512]);                                     \
    gload16(gB0 + o_, &Bbuf[BUF][KK][(2 * wv + 0) * 512]);                           \
    gload16(gB1 + o_, &Bbuf[BUF][KK][(2 * wv + 1) * 512]); } while (0)
#define RDF(CUR, KK) do {                                                            \
    _Pragma("unroll") for (int m_ = 0; m_ < 4; ++m_)                                 \
      af[m_] = *(const short8*)&Abuf[CUR][KK][(wr * 4 + m_) * 512 + lane * 8];       \
    _Pragma("unroll") for (int n_ = 0; n_ < 4; ++n_)                                 \
      bfr[n_] = *(const short8*)&Bbuf[CUR][KK][(wc * 4 + n_) * 512 + lane * 8]; } while (0)
#define MMQ() _Pragma("unroll") for (int m_ = 0; m_ < 4; ++m_)                       \
    _Pragma("unroll") for (int n_ = 0; n_ < 4; ++n_)                                 \
      acc[m_][n_] = mfma16(af[m_], bfr[n_], acc[m_][n_]);

  STG(0, 0, 0); STG(0, 1, 0); STG(1, 0, 1);
  VM6; BARR; SB0;

  for (int T = 0; T < nT; ++T) {
    const int cur = T & 1;
    // phase (T,0): read [cur][0]; stage (T+1,kk1)
    RDF(cur, 0);
    if (T + 1 < nT) STG(cur ^ 1, 1, T + 1);
    BARR; LGKM0; SB0;
    PRIO1; MMQ(); PRIO0;
    if (T + 1 < nT) { VM6; } else { VM0; }
    BARR; SB0;
    // phase (T,1): read [cur][1]; stage (T+2,kk0)
    RDF(cur, 1);
    if (T + 2 < nT) STG(cur, 0, T + 2);
    BARR; LGKM0; SB0;
    PRIO1; MMQ(); PRIO0;
    if (T + 2 < nT) { VM6; } else if (T + 1 < nT) { VM3; }
    BARR; SB0;
  }
#undef STG
#undef RDF
#undef MMQ

#pragma unroll
  for (int m = 0; m < 4; ++m) {
#pragma unroll
    for (int n = 0; n < 4; ++n) {
      const int col = (int)brow0 + wc * 64 + n * 16 + r;
      const float bv = bias[col];
#pragma unroll
      for (int i = 0; i < 4; ++i) {
        const size_t row = arow0 + wr * 64 + m * 16 + g * 4 + i;
        float v = acc[m][n][i] + bv;
        if (EPI == EPI_GELU) v = 0.5f * v * (1.f + erff(v * 0.70710678118f));
        if (EPI == EPI_RES) v += res[row * ldC + col];
        if (OF32) ((float*)Cv)[row * ldC + col] = v;
        else ((unsigned short*)Cv)[row * ldC + col] = f2b(v);
      }
    }
  }
}

// ---------------- Sliding-window attention: one wg per (b,h,qblock of 128) ----------------
// qkv layout: [8192][6144] bf16 (fused QKV buffer, attention half at cols 0..3071):
// q = cols 0..1023, k = 1024..2047, v = 2048..3071, head h at h*64.
__global__ __launch_bounds__(256) void swa_kernel(
    const unsigned short* __restrict__ qkv, unsigned short* __restrict__ outc) {
  __shared__ __attribute__((aligned(16))) unsigned short Ks[256 * 64];   // swizzled [s][e]
  __shared__ __attribute__((aligned(16))) unsigned short Vt[64 * 264];   // [e][s]
  __shared__ __attribute__((aligned(16))) unsigned short Ps[128 * 264];  // [r][s]
  __shared__ __attribute__((aligned(16))) float dn[128];
  const int bid = blockIdx.x;
  const int qb = bid & 31, h = (bid >> 5) & 15, b = bid >> 9;
  const long btok = (long)b * 4096;
  const long tok0 = btok + (long)qb * 128;
  const int tid = threadIdx.x, lane = tid & 63, wv = tid >> 6;
  const int g = lane >> 4, r = lane & 15;

#pragma unroll
  for (int i = 0; i < 8; ++i) {  // K stage: 16B chunks, chunk-XOR swizzle over 8 chunks/row
    int chunk = (wv * 8 + i) * 64 + lane;
    int s = chunk >> 3, cc = (chunk & 7) ^ (s & 7);
    long kt = tok0 - 128 + s; if (kt < btok) kt = btok;  // block 0: masked anyway
    gload16(&qkv[(size_t)kt * 6144 + 1024 + h * 64 + cc * 8], &Ks[(wv * 8 + i) * 512]);
  }
#pragma unroll
  for (int i = 0; i < 8; ++i) {  // V transposed stage
    int chunk = i * 256 + tid;
    int s = chunk >> 3, e8 = chunk & 7;
    long kt = tok0 - 128 + s; if (kt < btok) kt = btok;
    u16x8 u = *(const u16x8*)&qkv[(size_t)kt * 6144 + 2048 + h * 64 + e8 * 8];
#pragma unroll
    for (int j = 0; j < 8; ++j) Vt[(e8 * 8 + j) * 264 + s] = u[j];
  }
  short8 qf[2][2];  // Q frags direct from global
#pragma unroll
  for (int m = 0; m < 2; ++m)
#pragma unroll
    for (int kc = 0; kc < 2; ++kc)
      qf[m][kc] = *(const short8*)&qkv[(size_t)(tok0 + wv * 32 + m * 16 + r) * 6144 + h * 64 + kc * 32 + g * 8];
  __syncthreads();

  float rs[2][4] = {};
  for (int n = 0; n < 16; ++n) {
    const int srow = n * 16 + r;
    short8 kf0 = *(const short8*)&Ks[srow * 64 + ((g) ^ (srow & 7)) * 8];
    short8 kf1 = *(const short8*)&Ks[srow * 64 + ((4 + g) ^ (srow & 7)) * 8];
#pragma unroll
    for (int m = 0; m < 2; ++m) {
      f32x4 acc = {0.f, 0.f, 0.f, 0.f};
      acc = mfma16(qf[m][0], kf0, acc);
      acc = mfma16(qf[m][1], kf1, acc);
#pragma unroll
      for (int i = 0; i < 4; ++i) {
        int rr = wv * 32 + m * 16 + g * 4 + i;
        int ss = n * 16 + r;
        bool valid = (ss >= rr + 1) && (ss <= rr + 128) && (qb > 0 || ss >= 128);
        float p = valid ? __expf(acc[i] * 0.125f) : 0.f;  // scores small: no max-sub needed
        rs[m][i] += p;
        Ps[rr * 264 + ss] = f2b(p);
      }
    }
  }
#pragma unroll
  for (int m = 0; m < 2; ++m)
#pragma unroll
    for (int i = 0; i < 4; ++i) {
      float v = rs[m][i];
      v += __shfl_xor(v, 1); v += __shfl_xor(v, 2);
      v += __shfl_xor(v, 4); v += __shfl_xor(v, 8);
      if (r == i) dn[wv * 32 + m * 16 + g * 4 + i] = v;
    }
  __syncthreads();

  f32x4 oacc[2][4] = {};
  for (int sc = 0; sc < 8; ++sc) {
    short8 pf[2], vf[4];
#pragma unroll
    for (int m = 0; m < 2; ++m)
      pf[m] = *(const short8*)&Ps[(wv * 32 + m * 16 + r) * 264 + sc * 32 + g * 8];
#pragma unroll
    for (int n = 0; n < 4; ++n)
      vf[n] = *(const short8*)&Vt[(n * 16 + r) * 264 + sc * 32 + g * 8];
#pragma unroll
    for (int m = 0; m < 2; ++m)
#pragma unroll
      for (int n = 0; n < 4; ++n)
        oacc[m][n] = mfma16(pf[m], vf[n], oacc[m][n]);
  }
#pragma unroll
  for (int m = 0; m < 2; ++m) {
    f32x4 dv = *(const f32x4*)&dn[wv * 32 + m * 16 + g * 4];
#pragma unroll
    for (int n = 0; n < 4; ++n) {
      int col = h * 64 + n * 16 + r;
#pragma unroll
      for (int i = 0; i < 4; ++i) {
        size_t row = (size_t)(tok0 + wv * 32 + m * 16 + g * 4 + i);
        outc[row * 2048 + col] = f2b(oacc[m][n][i] / dv[i]);
      }
    }
  }
}

// ---------------- Linear attention pass 1: per-chunk KVt[f][e], kz[e] ----------------
// qkv points at the S-half (fused buffer + 3072), row stride 6144.
__global__ __launch_bounds__(256) void lin_pass1(
    const unsigned short* __restrict__ qkv, float* __restrict__ KVt, float* __restrict__ kz) {
  __shared__ __attribute__((aligned(16))) unsigned short kf[128 * 72];
  __shared__ __attribute__((aligned(16))) unsigned short vs[128 * 72];
  const int bid = blockIdx.x;
  const int ch = bid & 31, h = (bid >> 5) & 15, b = bid >> 9;
  const size_t tok0 = (size_t)b * 4096 + (size_t)ch * 128;
  const int tid = threadIdx.x;
#pragma unroll
  for (int i = 0; i < 4; ++i) {
    int c = i * 256 + tid;
    int row = c >> 3, e8 = c & 7;
    u16x8 uk = *(const u16x8*)&qkv[(tok0 + row) * 6144 + 1024 + h * 64 + e8 * 8];
    u16x8 uv = *(const u16x8*)&qkv[(tok0 + row) * 6144 + 2048 + h * 64 + e8 * 8];
    u16x8 tk;
#pragma unroll
    for (int j = 0; j < 8; ++j) {
      float x = b2f(uk[j]);
      x = (x > 0.f) ? x : expm1f(x);  // elu
      tk[j] = f2b(x + 1.0001f);
    }
    *(u16x8*)&kf[row * 72 + e8 * 8] = tk;
    *(u16x8*)&vs[row * 72 + e8 * 8] = uv;
  }
  __syncthreads();
  const int e0 = (tid & 15) * 4, f0 = (tid >> 4) * 4;
  float acc[4][4] = {};
  for (int c = 0; c < 128; ++c) {
    u16x4 ku = *(const u16x4*)&kf[c * 72 + e0];
    u16x4 vu = *(const u16x4*)&vs[c * 72 + f0];
    float ke[4], vv[4];
#pragma unroll
    for (int j = 0; j < 4; ++j) { ke[j] = b2f(ku[j]); vv[j] = b2f(vu[j]); }
#pragma unroll
    for (int jf = 0; jf < 4; ++jf)
#pragma unroll
      for (int je = 0; je < 4; ++je)
        acc[jf][je] += vv[jf] * ke[je];
  }
  const size_t base = (size_t)bid * 4096;
#pragma unroll
  for (int jf = 0; jf < 4; ++jf) {
    f32x4 o = {acc[jf][0], acc[jf][1], acc[jf][2], acc[jf][3]};
    *(f32x4*)&KVt[base + (f0 + jf) * 64 + e0] = o;
  }
  if (tid < 64) {
    float s = 0.f;
    for (int c = 0; c < 128; ++c) s += b2f(kf[c * 72 + tid]);
    kz[(size_t)bid * 64 + tid] = s;
  }
}

// ---------------- pass 2: per (b,h) exclusive prefix over 32 chunks (in place) ----------------
__global__ __launch_bounds__(256) void lin_pass2(float* __restrict__ KVt, float* __restrict__ kz) {
  const int bh = blockIdx.x;
  const int tid = threadIdx.x;
  f32x4 run[4] = {};
  for (int ch = 0; ch < 32; ++ch) {
    const size_t base = ((size_t)bh * 32 + ch) * 4096;
#pragma unroll
    for (int i = 0; i < 4; ++i) {
      float* p = &KVt[base + (size_t)(i * 256 + tid) * 4];
      f32x4 c = *(f32x4*)p;
      *(f32x4*)p = run[i];
      run[i] += c;
    }
  }
  if (tid < 64) {
    float rz = 0.f;
    for (int ch = 0; ch < 32; ++ch) {
      float* p = &kz[((size_t)bh * 32 + ch) * 64 + tid];
      float c = *p; *p = rz; rz += c;
    }
  }
}

// ---------------- pass 3: o = (q@S_prev + tril(qk^T)@v) / (q.z_prev + rowsumA + 1e-6) ----------------
__global__ __launch_bounds__(256) void lin_pass3(
    const unsigned short* __restrict__ qkv, const float* __restrict__ KVt,
    const float* __restrict__ kz, unsigned short* __restrict__ outc) {
  __shared__ __attribute__((aligned(16))) unsigned short qf[128 * 72];
  __shared__ __attribute__((aligned(16))) unsigned short kf[128 * 72];
  __shared__ __attribute__((aligned(16))) unsigned short vt[64 * 136];
  __shared__ __attribute__((aligned(16))) unsigned short st[64 * 72];
  __shared__ __attribute__((aligned(16))) unsigned short am[128 * 136];
  __shared__ __attribute__((aligned(16))) float zs[64];
  __shared__ __attribute__((aligned(16))) float dnl[128];
  const int bid = blockIdx.x;
  const int ch = bid & 31, h = (bid >> 5) & 15, b = bid >> 9;
  const size_t tok0 = (size_t)b * 4096 + (size_t)ch * 128;
  const int tid = threadIdx.x, lane = tid & 63, wv = tid >> 6;
  const int g = lane >> 4, r = lane & 15;

#pragma unroll
  for (int i = 0; i < 4; ++i) {
    int c = i * 256 + tid;
    int row = c >> 3, e8 = c & 7;
    u16x8 uq = *(const u16x8*)&qkv[(tok0 + row) * 6144 + h * 64 + e8 * 8];
    u16x8 uk = *(const u16x8*)&qkv[(tok0 + row) * 6144 + 1024 + h * 64 + e8 * 8];
    u16x8 uv = *(const u16x8*)&qkv[(tok0 + row) * 6144 + 2048 + h * 64 + e8 * 8];
    u16x8 tq, tk;
#pragma unroll
    for (int j = 0; j < 8; ++j) {
      float x = b2f(uq[j]) * 0.125f;
      x = (x > 0.f) ? x : expm1f(x);
      tq[j] = f2b(x + 1.0001f);
      float y = b2f(uk[j]);
      y = (y > 0.f) ? y : expm1f(y);
      tk[j] = f2b(y + 1.0001f);
    }
    *(u16x8*)&qf[row * 72 + e8 * 8] = tq;
    *(u16x8*)&kf[row * 72 + e8 * 8] = tk;
#pragma unroll
    for (int j = 0; j < 8; ++j) vt[(e8 * 8 + j) * 136 + row] = uv[j];
  }
#pragma unroll
  for (int i = 0; i < 2; ++i) {  // S_prev^T (f-major) f32 -> bf16 LDS
    int idx = i * 256 + tid;
    int f = idx >> 3, e8 = idx & 7;
    f32x4 s0 = *(const f32x4*)&KVt[(size_t)bid * 4096 + f * 64 + e8 * 8];
    f32x4 s1 = *(const f32x4*)&KVt[(size_t)bid * 4096 + f * 64 + e8 * 8 + 4];
    u16x8 t;
#pragma unroll
    for (int j = 0; j < 4; ++j) { t[j] = f2b(s0[j]); t[4 + j] = f2b(s1[j]); }
    *(u16x8*)&st[f * 72 + e8 * 8] = t;
  }
  if (tid < 64) zs[tid] = kz[(size_t)bid * 64 + tid];
  __syncthreads();

  short8 aq[2][2];
#pragma unroll
  for (int m = 0; m < 2; ++m)
#pragma unroll
    for (int kc = 0; kc < 2; ++kc)
      aq[m][kc] = *(const short8*)&qf[(wv * 32 + m * 16 + r) * 72 + kc * 32 + g * 8];

  float rsA[2][4] = {};
  for (int n = 0; n < 8; ++n) {  // A = tril(qf @ kf^T), bf16 to LDS + rowsums
    short8 bk0 = *(const short8*)&kf[(n * 16 + r) * 72 + g * 8];
    short8 bk1 = *(const short8*)&kf[(n * 16 + r) * 72 + 32 + g * 8];
#pragma unroll
    for (int m = 0; m < 2; ++m) {
      f32x4 acc = {0.f, 0.f, 0.f, 0.f};
      acc = mfma16(aq[m][0], bk0, acc);
      acc = mfma16(aq[m][1], bk1, acc);
#pragma unroll
      for (int i = 0; i < 4; ++i) {
        int rr = wv * 32 + m * 16 + g * 4 + i;
        int cc = n * 16 + r;
        float v = (cc <= rr) ? acc[i] : 0.f;
        rsA[m][i] += v;
        am[rr * 136 + cc] = f2b(v);
      }
    }
  }
#pragma unroll
  for (int m = 0; m < 2; ++m)
#pragma unroll
    for (int i = 0; i < 4; ++i) {
      float v = rsA[m][i];
      v += __shfl_xor(v, 1); v += __shfl_xor(v, 2);
      v += __shfl_xor(v, 4); v += __shfl_xor(v, 8);
      if (r == i) dnl[wv * 32 + m * 16 + g * 4 + i] = v;
    }
  __syncthreads();

  if (tid < 128) {  // den = rowsumA + qf . z_prev
    float s = dnl[tid];
#pragma unroll
    for (int e = 0; e < 64; e += 4) {
      u16x4 qv = *(const u16x4*)&qf[tid * 72 + e];
      s += b2f(qv[0]) * zs[e] + b2f(qv[1]) * zs[e + 1] + b2f(qv[2]) * zs[e + 2] + b2f(qv[3]) * zs[e + 3];
    }
    dnl[tid] = s + 1e-6f;
  }

  f32x4 oac[2][4] = {};
#pragma unroll
  for (int kc = 0; kc < 2; ++kc) {  // num += qf @ S_prev
    short8 sf[4];
#pragma unroll
    for (int n = 0; n < 4; ++n) sf[n] = *(const short8*)&st[(n * 16 + r) * 72 + kc * 32 + g * 8];
#pragma unroll
    for (int m = 0; m < 2; ++m)
#pragma unroll
      for (int n = 0; n < 4; ++n)
        oac[m][n] = mfma16(aq[m][kc], sf[n], oac[m][n]);
  }
  for (int c4 = 0; c4 < 4; ++c4) {  // num += A @ v
    short8 pa[2], vb[4];
#pragma unroll
    for (int m = 0; m < 2; ++m)
      pa[m] = *(const short8*)&am[(wv * 32 + m * 16 + r) * 136 + c4 * 32 + g * 8];
#pragma unroll
    for (int n = 0; n < 4; ++n)
      vb[n] = *(const short8*)&vt[(n * 16 + r) * 136 + c4 * 32 + g * 8];
#pragma unroll
    for (int m = 0; m < 2; ++m)
#pragma unroll
      for (int n = 0; n < 4; ++n)
        oac[m][n] = mfma16(pa[m], vb[n], oac[m][n]);
  }
  __syncthreads();
#pragma unroll
  for (int m = 0; m < 2; ++m) {
    f32x4 dv = *(const f32x4*)&dnl[wv * 32 + m * 16 + g * 4];
#pragma unroll
    for (int n = 0; n < 4; ++n) {
      int col = 1024 + h * 64 + n * 16 + r;
#pragma unroll
      for (int i = 0; i < 4; ++i) {
        size_t row = tok0 + wv * 32 + m * 16 + g * 4 + i;
        outc[row * 2048 + col] = f2b(oac[m][n][i] / dv[i]);
      }
    }
  }
}

// ---------------- host ----------------
extern "C" void kernel_launch(void* const* d_in, const int* in_sizes, int n_in,
                              void* d_out, int out_size, void* d_ws, size_t ws_size,
                              hipStream_t stream) {
  (void)in_sizes; (void)n_in; (void)out_size; (void)ws_size;
  const float* x      = (const float*)d_in[0];
  const float* g1     = (const float*)d_in[1];
  const float* b1     = (const float*)d_in[2];
  const float* Wqkv_a = (const float*)d_in[3];
  const float* bqkv_a = (const float*)d_in[4];
  const float* Wp_a   = (const float*)d_in[5];
  const float* bp_a   = (const float*)d_in[6];
  const float* Wqkv_s = (const float*)d_in[7];
  const float* bqkv_s = (const float*)d_in[8];
  const float* Wo_s   = (const float*)d_in[9];
  const float* bo_s   = (const float*)d_in[10];
  const float* Wo     = (const float*)d_in[11];
  const float* bo     = (const float*)d_in[12];
  const float* gm     = (const float*)d_in[13];
  const float* bm     = (const float*)d_in[14];
  const float* W1     = (const float*)d_in[15];
  const float* b1m    = (const float*)d_in[16];
  const float* W2     = (const float*)d_in[17];
  const float* b2m    = (const float*)d_in[18];
  float* out = (float*)d_out;

  char* ws = (char*)d_ws;
  size_t off = 0;
  auto alloc = [&](size_t bytes) { char* p = ws + off; off += (bytes + 255) & ~(size_t)255; return p; };
  unsigned short* wTaS  = (unsigned short*)alloc((size_t)6144 * 1024 * 2);  // [Wqkv_a^T ; Wqkv_s^T]
  unsigned short* wTpo  = (unsigned short*)alloc((size_t)1024 * 2048 * 2);
  unsigned short* wTo   = (unsigned short*)alloc((size_t)1024 * 1024 * 2);
  unsigned short* wT1   = (unsigned short*)alloc((size_t)4096 * 1024 * 2);
  unsigned short* wT2   = (unsigned short*)alloc((size_t)1024 * 4096 * 2);
  float*          bcomb = (float*)alloc(1024 * 4);
  float*          bcat  = (float*)alloc(6144 * 4);
  unsigned short* xn    = (unsigned short*)alloc((size_t)8192 * 1024 * 2);  // reused as h
  unsigned short* qkvAS = (unsigned short*)alloc((size_t)8192 * 6144 * 2);  // fused; reused as gbuf
  unsigned short* comb  = (unsigned short*)alloc((size_t)8192 * 2048 * 2);  // reused as x1 (f32)
  float*          kvt   = (float*)alloc((size_t)1024 * 4096 * 4);           // reused as sum (bf16)
  float*          kzp   = (float*)alloc((size_t)1024 * 64 * 4);
  unsigned short* gbuf  = qkvAS;
  unsigned short* sum   = (unsigned short*)kvt;
  unsigned short* h_    = xn;
  float*          x1    = (float*)comb;  // comb dead once sum is computed

  transpose_w<<<dim3(16, 48), 256, 0, stream>>>(Wqkv_a, wTaS, 3072, 1024, 0);
  transpose_w<<<dim3(16, 48), 256, 0, stream>>>(Wqkv_s, wTaS + (size_t)3072 * 1024, 3072, 1024, 0);
  transpose_w<<<dim3(16, 16), 256, 0, stream>>>(Wp_a, wTpo, 1024, 2048, 0);
  transpose_w<<<dim3(16, 16), 256, 0, stream>>>(Wo_s, wTpo, 1024, 2048, 1024);
  transpose_w<<<dim3(16, 16), 256, 0, stream>>>(Wo, wTo, 1024, 1024, 0);
  transpose_w<<<dim3(16, 64), 256, 0, stream>>>(W1, wT1, 4096, 1024, 0);
  transpose_w<<<dim3(64, 16), 256, 0, stream>>>(W2, wT2, 1024, 4096, 0);
  bias_comb<<<4, 256, 0, stream>>>(bp_a, bo_s, bcomb);
  bias_cat<<<24, 256, 0, stream>>>(bqkv_a, bqkv_s, bcat, 3072);

  ln_kernel<<<8192, 256, 0, stream>>>(x, g1, b1, xn);
  // fused QKV: M=8192, N=6144, K=1024 -> big 256x256, grid 32x24
  gemm_big<EPI_STORE, 0><<<dim3(32, 24), 512, 0, stream>>>(xn, wTaS, bcat, qkvAS, nullptr, 1024, 1024, 6144);
  swa_kernel<<<1024, 256, 0, stream>>>(qkvAS, comb);
  lin_pass1<<<1024, 256, 0, stream>>>(qkvAS + 3072, kvt, kzp);
  lin_pass2<<<32, 256, 0, stream>>>(kvt, kzp);
  lin_pass3<<<1024, 256, 0, stream>>>(qkvAS + 3072, kvt, kzp, comb);
  // sum = [attn|ssm] @ [Wp_a;Wo_s] + (bp_a+bo_s): M=8192,N=1024,K=2048 -> small, grid 64x4
  gemm_sml<EPI_STORE, 0><<<dim3(64, 4), 512, 0, stream>>>(comb, wTpo, bcomb, sum, nullptr, 2048, 2048, 1024);
  // x1 = x + sum @ Wo + bo (f32 out): M=8192,N=1024,K=1024
  gemm_sml<EPI_RES, 1><<<dim3(64, 4), 512, 0, stream>>>(sum, wTo, bo, x1, x, 1024, 1024, 1024);
  ln_kernel<<<8192, 256, 0, stream>>>(x1, gm, bm, h_);
  // MLP1: M=8192,N=4096,K=1024 -> big, grid 32x16
  gemm_big<EPI_GELU, 0><<<dim3(32, 16), 512, 0, stream>>>(h_, wT1, b1m, gbuf, nullptr, 1024, 1024, 4096);
  // MLP2: M=8192,N=1024,K=4096 -> small, grid 64x4
  gemm_sml<EPI_RES, 1><<<dim3(64, 4), 512, 0, stream>>>(gbuf, wT2, b2m, out, x1, 4096, 4096, 1024);
}

// Round 12
// 589.460 us; speedup vs baseline: 1.2150x; 1.0391x over previous
//
#include <hip/hip_runtime.h>
#include <hip/hip_bf16.h>
#include <math.h>

typedef __hip_bfloat16 bf16;
typedef float f32x4 __attribute__((ext_vector_type(4)));
typedef short short8 __attribute__((ext_vector_type(8)));
typedef unsigned short u16x4 __attribute__((ext_vector_type(4)));
typedef unsigned short u16x8 __attribute__((ext_vector_type(8)));

#define AS1 __attribute__((address_space(1)))
#define AS3 __attribute__((address_space(3)))

__device__ __forceinline__ void gload16(const void* g, void* l) {
  __builtin_amdgcn_global_load_lds((const AS1 unsigned int*)g, (AS3 unsigned int*)l, 16, 0, 0);
}
__device__ __forceinline__ float b2f(unsigned short u) {
  union { unsigned int i; float f; } c; c.i = ((unsigned int)u) << 16; return c.f;
}
__device__ __forceinline__ unsigned short f2b(float f) {
  bf16 h = __float2bfloat16(f);
  unsigned short s; __builtin_memcpy(&s, &h, 2); return s;
}
__device__ __forceinline__ f32x4 mfma16(short8 a, short8 b, f32x4 c) {
  return __builtin_amdgcn_mfma_f32_16x16x32_bf16(a, b, c, 0, 0, 0);
}

#define BARR asm volatile("s_barrier" ::: "memory")
#define LGKM0 asm volatile("s_waitcnt lgkmcnt(0)" ::: "memory")
#define VM8 asm volatile("s_waitcnt vmcnt(8)" ::: "memory")
#define VM6 asm volatile("s_waitcnt vmcnt(6)" ::: "memory")
#define VM4 asm volatile("s_waitcnt vmcnt(4)" ::: "memory")
#define VM3 asm volatile("s_waitcnt vmcnt(3)" ::: "memory")
#define VM0 asm volatile("s_waitcnt vmcnt(0)" ::: "memory")
#define SB0 __builtin_amdgcn_sched_barrier(0)
#define PRIO1 __builtin_amdgcn_s_setprio(1)
#define PRIO0 __builtin_amdgcn_s_setprio(0)

// ---------------- LayerNorm: f32 in -> bf16 out, one block per 1024-wide row ----------------
__global__ __launch_bounds__(256) void ln_kernel(
    const float* __restrict__ X, const float* __restrict__ G,
    const float* __restrict__ Bb, unsigned short* __restrict__ Y) {
  __shared__ float red[8];
  const size_t row = blockIdx.x;
  const int tid = threadIdx.x;
  f32x4 v = *(const f32x4*)&X[row * 1024 + tid * 4];
  float s = 0.f, sq = 0.f;
#pragma unroll
  for (int j = 0; j < 4; ++j) { s += v[j]; sq += v[j] * v[j]; }
#pragma unroll
  for (int o = 1; o < 64; o <<= 1) { s += __shfl_xor(s, o); sq += __shfl_xor(sq, o); }
  if ((tid & 63) == 0) { red[tid >> 6] = s; red[4 + (tid >> 6)] = sq; }
  __syncthreads();
  s = red[0] + red[1] + red[2] + red[3];
  sq = red[4] + red[5] + red[6] + red[7];
  const float mean = s * (1.f / 1024.f);
  const float var = sq * (1.f / 1024.f) - mean * mean;
  const float inv = 1.f / sqrtf(var + 1e-5f);
  f32x4 gv = *(const f32x4*)&G[tid * 4];
  f32x4 bv = *(const f32x4*)&Bb[tid * 4];
  u16x4 ov;
#pragma unroll
  for (int j = 0; j < 4; ++j) ov[j] = f2b((v[j] - mean) * inv * gv[j] + bv[j]);
  *(u16x4*)&Y[row * 1024 + tid * 4] = ov;
}

// ---------------- Batched weight transpose: 7 transposes in ONE dispatch ----------------
// Same per-tile body as the old transpose_w (bit-identical output); flat grid decoded via a
// by-value descriptor table. Saves 6 inter-dispatch gaps on the captured stream.
struct TW7 {
  const float* S[7];
  unsigned short* D[7];
  int N[7], dld[7], doff[7], gx[7];
  int start[8];
};
__global__ __launch_bounds__(256) void transpose_w7(TW7 tw) {
  __shared__ __attribute__((aligned(16))) unsigned short t[64][72];
  const int bid = blockIdx.x;
  int c = 0;
#pragma unroll
  for (int j = 0; j < 7; ++j)
    if (bid >= tw.start[j]) c = j;
  const int local = bid - tw.start[c];
  const int k0 = (local % tw.gx[c]) * 64, n0 = (local / tw.gx[c]) * 64;
  const float* S = tw.S[c];
  unsigned short* D = tw.D[c];
  const int N = tw.N[c], dld = tw.dld[c], doff = tw.doff[c];
  const int tid = threadIdx.x;
#pragma unroll
  for (int i = 0; i < 2; ++i) {
    int cc = i * 256 + tid;
    int row = cc >> 3, c8 = cc & 7;
    f32x4 a = *(const f32x4*)&S[(size_t)(k0 + row) * N + n0 + c8 * 8];
    f32x4 b = *(const f32x4*)&S[(size_t)(k0 + row) * N + n0 + c8 * 8 + 4];
    u16x8 o;
#pragma unroll
    for (int j = 0; j < 4; ++j) { o[j] = f2b(a[j]); o[4 + j] = f2b(b[j]); }
    *(u16x8*)&t[row][c8 * 8] = o;
  }
  __syncthreads();
#pragma unroll
  for (int i = 0; i < 2; ++i) {
    int cc = i * 256 + tid;
    int nrow = cc >> 3, k8 = cc & 7;
    u16x8 o;
#pragma unroll
    for (int j = 0; j < 8; ++j) o[j] = t[k8 * 8 + j][nrow];
    *(u16x8*)&D[(size_t)(n0 + nrow) * dld + doff + k0 + k8 * 8] = o;
  }
}

__global__ __launch_bounds__(256) void bias_comb(
    const float* __restrict__ a, const float* __restrict__ b, float* __restrict__ o) {
  int i = blockIdx.x * 256 + threadIdx.x;
  o[i] = a[i] + b[i];
}

// concat bias: o[0..2N) = a | b
__global__ __launch_bounds__(256) void bias_cat(
    const float* __restrict__ a, const float* __restrict__ b, float* __restrict__ o, int N) {
  int i = blockIdx.x * 256 + threadIdx.x;
  o[i] = (i < N) ? a[i] : b[i - N];
}

#define EPI_STORE 0
#define EPI_GELU 1
#define EPI_RES 2

// ---------------- GEMM big: 256x256, BK=64, DEEP counted-vmcnt (lead-3), 2x32 MFMA --------
// Best-measured GEMM config (R10/R11). Structural plateau: vmcnt depth 1 vs 3 both ~132 us,
// MfmaUtil 33% — residual is barrier/lgkm lockstep at 1 block/CU. Do not touch.
template <int EPI, int OF32>
__global__ __launch_bounds__(512, 2) void gemm_big(
    const unsigned short* __restrict__ A, const unsigned short* __restrict__ Bt,
    const float* __restrict__ bias, void* __restrict__ Cv,
    const float* __restrict__ res, int K, int ldA, int ldC) {
  __shared__ __attribute__((aligned(16))) unsigned short Abuf[2][2][16 * 512];
  __shared__ __attribute__((aligned(16))) unsigned short Bbuf[2][2][16 * 512];
  const int tid = threadIdx.x, lane = tid & 63, wv = tid >> 6;
  const int g = lane >> 4, r = lane & 15;
  const int wr = wv >> 2, wc = wv & 3;
  const size_t arow0 = (size_t)blockIdx.x * 256;
  const size_t brow0 = (size_t)blockIdx.y * 256;
  const size_t ldAs = (size_t)ldA, Ksz = (size_t)K;
  // frag f covers rows f*16+(l&15), k kk*32+(l>>4)*8; wave wv stages frags {2wv, 2wv+1}
  const unsigned short* gA0 = A + (arow0 + (size_t)((2 * wv + 0) * 16 + r)) * ldAs + g * 8;
  const unsigned short* gA1 = A + (arow0 + (size_t)((2 * wv + 1) * 16 + r)) * ldAs + g * 8;
  const unsigned short* gB0 = Bt + (brow0 + (size_t)((2 * wv + 0) * 16 + r)) * Ksz + g * 8;
  const unsigned short* gB1 = Bt + (brow0 + (size_t)((2 * wv + 1) * 16 + r)) * Ksz + g * 8;
  const int nT = K >> 6;  // >= 16 at all call sites
  f32x4 acc[8][4] = {};
  short8 af[8], bfr[4];

#define STG(BUF, KK, T_) do { size_t o_ = (size_t)(T_) * 64 + (KK) * 32;            \
    gload16(gA0 + o_, &Abuf[BUF][KK][(2 * wv + 0) * 512]);                           \
    gload16(gA1 + o_, &Abuf[BUF][KK][(2 * wv + 1) * 512]);                           \
    gload16(gB0 + o_, &Bbuf[BUF][KK][(2 * wv + 0) * 512]);                           \
    gload16(gB1 + o_, &Bbuf[BUF][KK][(2 * wv + 1) * 512]); } while (0)
#define RDF(CUR, KK) do {                                                            \
    _Pragma("unroll") for (int m_ = 0; m_ < 8; ++m_)                                 \
      af[m_] = *(const short8*)&Abuf[CUR][KK][(wr * 8 + m_) * 512 + lane * 8];       \
    _Pragma("unroll") for (int n_ = 0; n_ < 4; ++n_)                                 \
      bfr[n_] = *(const short8*)&Bbuf[CUR][KK][(wc * 4 + n_) * 512 + lane * 8]; } while (0)
#define MMQ() _Pragma("unroll") for (int m_ = 0; m_ < 8; ++m_)                       \
    _Pragma("unroll") for (int n_ = 0; n_ < 4; ++n_)                                 \
      acc[m_][n_] = mfma16(af[m_], bfr[n_], acc[m_][n_]);

  // prologue: stage G0=(0,k0), G1=(0,k1), G2=(1,k0); VM8 retires G0, leaves G1,G2 (8)
  STG(0, 0, 0); STG(0, 1, 0); STG(1, 0, 1);
  VM8; BARR; SB0;

  for (int T = 0; T < nT; ++T) {
    const int cur = T & 1;
    // phase (T,0): read [cur][0]; stage (T+1,kk1) -> [cur^1][1]
    RDF(cur, 0);
    if (T + 1 < nT) STG(cur ^ 1, 1, T + 1);
    BARR; LGKM0; SB0;
    PRIO1; MMQ(); PRIO0;
    if (T + 1 < nT) { VM8; } else { VM0; }
    BARR; SB0;
    // phase (T,1): read [cur][1]; stage (T+2,kk0) -> [cur][0]
    RDF(cur, 1);
    if (T + 2 < nT) STG(cur, 0, T + 2);
    BARR; LGKM0; SB0;
    PRIO1; MMQ(); PRIO0;
    if (T + 2 < nT) { VM8; } else if (T + 1 < nT) { VM4; }
    BARR; SB0;
  }
#undef STG
#undef RDF
#undef MMQ

#pragma unroll
  for (int m = 0; m < 8; ++m) {
#pragma unroll
    for (int n = 0; n < 4; ++n) {
      const int col = (int)brow0 + wc * 64 + n * 16 + r;
      const float bv = bias[col];
#pragma unroll
      for (int i = 0; i < 4; ++i) {
        const size_t row = arow0 + wr * 128 + m * 16 + g * 4 + i;
        float v = acc[m][n][i] + bv;
        if (EPI == EPI_GELU) v = 0.5f * v * (1.f + erff(v * 0.70710678118f));
        if (EPI == EPI_RES) v += res[row * ldC + col];
        if (OF32) ((float*)Cv)[row * ldC + col] = v;
        else ((unsigned short*)Cv)[row * ldC + col] = f2b(v);
      }
    }
  }
}

// ---------------- GEMM small: 128x256, BK=64, DEEP counted-vmcnt (lead-3) -----------------
template <int EPI, int OF32>
__global__ __launch_bounds__(512, 2) void gemm_sml(
    const unsigned short* __restrict__ A, const unsigned short* __restrict__ Bt,
    const float* __restrict__ bias, void* __restrict__ Cv,
    const float* __restrict__ res, int K, int ldA, int ldC) {
  __shared__ __attribute__((aligned(16))) unsigned short Abuf[2][2][8 * 512];
  __shared__ __attribute__((aligned(16))) unsigned short Bbuf[2][2][16 * 512];
  const int tid = threadIdx.x, lane = tid & 63, wv = tid >> 6;
  const int g = lane >> 4, r = lane & 15;
  const int wr = wv >> 2, wc = wv & 3;
  const size_t arow0 = (size_t)blockIdx.x * 128;
  const size_t brow0 = (size_t)blockIdx.y * 256;
  const size_t ldAs = (size_t)ldA, Ksz = (size_t)K;
  const unsigned short* gAs = A + (arow0 + (size_t)(wv * 16 + r)) * ldAs + g * 8;
  const unsigned short* gB0 = Bt + (brow0 + (size_t)((2 * wv + 0) * 16 + r)) * Ksz + g * 8;
  const unsigned short* gB1 = Bt + (brow0 + (size_t)((2 * wv + 1) * 16 + r)) * Ksz + g * 8;
  const int nT = K >> 6;  // >= 16 at all call sites
  f32x4 acc[4][4] = {};
  short8 af[4], bfr[4];

#define STG(BUF, KK, T_) do { size_t o_ = (size_t)(T_) * 64 + (KK) * 32;            \
    gload16(gAs + o_, &Abuf[BUF][KK][wv * 512]);                                     \
    gload16(gB0 + o_, &Bbuf[BUF][KK][(2 * wv + 0) * 512]);                           \
    gload16(gB1 + o_, &Bbuf[BUF][KK][(2 * wv + 1) * 512]); } while (0)
#define RDF(CUR, KK) do {                                                            \
    _Pragma("unroll") for (int m_ = 0; m_ < 4; ++m_)                                 \
      af[m_] = *(const short8*)&Abuf[CUR][KK][(wr * 4 + m_) * 512 + lane * 8];       \
    _Pragma("unroll") for (int n_ = 0; n_ < 4; ++n_)                                 \
      bfr[n_] = *(const short8*)&Bbuf[CUR][KK][(wc * 4 + n_) * 512 + lane * 8]; } while (0)
#define MMQ() _Pragma("unroll") for (int m_ = 0; m_ < 4; ++m_)                       \
    _Pragma("unroll") for (int n_ = 0; n_ < 4; ++n_)                                 \
      acc[m_][n_] = mfma16(af[m_], bfr[n_], acc[m_][n_]);

  STG(0, 0, 0); STG(0, 1, 0); STG(1, 0, 1);
  VM6; BARR; SB0;

  for (int T = 0; T < nT; ++T) {
    const int cur = T & 1;
    // phase (T,0): read [cur][0]; stage (T+1,kk1)
    RDF(cur, 0);
    if (T + 1 < nT) STG(cur ^ 1, 1, T + 1);
    BARR; LGKM0; SB0;
    PRIO1; MMQ(); PRIO0;
    if (T + 1 < nT) { VM6; } else { VM0; }
    BARR; SB0;
    // phase (T,1): read [cur][1]; stage (T+2,kk0)
    RDF(cur, 1);
    if (T + 2 < nT) STG(cur, 0, T + 2);
    BARR; LGKM0; SB0;
    PRIO1; MMQ(); PRIO0;
    if (T + 2 < nT) { VM6; } else if (T + 1 < nT) { VM3; }
    BARR; SB0;
  }
#undef STG
#undef RDF
#undef MMQ

#pragma unroll
  for (int m = 0; m < 4; ++m) {
#pragma unroll
    for (int n = 0; n < 4; ++n) {
      const int col = (int)brow0 + wc * 64 + n * 16 + r;
      const float bv = bias[col];
#pragma unroll
      for (int i = 0; i < 4; ++i) {
        const size_t row = arow0 + wr * 64 + m * 16 + g * 4 + i;
        float v = acc[m][n][i] + bv;
        if (EPI == EPI_GELU) v = 0.5f * v * (1.f + erff(v * 0.70710678118f));
        if (EPI == EPI_RES) v += res[row * ldC + col];
        if (OF32) ((float*)Cv)[row * ldC + col] = v;
        else ((unsigned short*)Cv)[row * ldC + col] = f2b(v);
      }
    }
  }
}

// ---------------- Sliding-window attention: one wg per (b,h,qblock of 128) ----------------
// qkv layout: [8192][6144] bf16 (fused QKV buffer, attention half at cols 0..3071):
// q = cols 0..1023, k = 1024..2047, v = 2048..3071, head h at h*64.
__global__ __launch_bounds__(256) void swa_kernel(
    const unsigned short* __restrict__ qkv, unsigned short* __restrict__ outc) {
  __shared__ __attribute__((aligned(16))) unsigned short Ks[256 * 64];   // swizzled [s][e]
  __shared__ __attribute__((aligned(16))) unsigned short Vt[64 * 264];   // [e][s]
  __shared__ __attribute__((aligned(16))) unsigned short Ps[128 * 264];  // [r][s]
  __shared__ __attribute__((aligned(16))) float dn[128];
  const int bid = blockIdx.x;
  const int qb = bid & 31, h = (bid >> 5) & 15, b = bid >> 9;
  const long btok = (long)b * 4096;
  const long tok0 = btok + (long)qb * 128;
  const int tid = threadIdx.x, lane = tid & 63, wv = tid >> 6;
  const int g = lane >> 4, r = lane & 15;

#pragma unroll
  for (int i = 0; i < 8; ++i) {  // K stage: 16B chunks, chunk-XOR swizzle over 8 chunks/row
    int chunk = (wv * 8 + i) * 64 + lane;
    int s = chunk >> 3, cc = (chunk & 7) ^ (s & 7);
    long kt = tok0 - 128 + s; if (kt < btok) kt = btok;  // block 0: masked anyway
    gload16(&qkv[(size_t)kt * 6144 + 1024 + h * 64 + cc * 8], &Ks[(wv * 8 + i) * 512]);
  }
#pragma unroll
  for (int i = 0; i < 8; ++i) {  // V transposed stage
    int chunk = i * 256 + tid;
    int s = chunk >> 3, e8 = chunk & 7;
    long kt = tok0 - 128 + s; if (kt < btok) kt = btok;
    u16x8 u = *(const u16x8*)&qkv[(size_t)kt * 6144 + 2048 + h * 64 + e8 * 8];
#pragma unroll
    for (int j = 0; j < 8; ++j) Vt[(e8 * 8 + j) * 264 + s] = u[j];
  }
  short8 qf[2][2];  // Q frags direct from global
#pragma unroll
  for (int m = 0; m < 2; ++m)
#pragma unroll
    for (int kc = 0; kc < 2; ++kc)
      qf[m][kc] = *(const short8*)&qkv[(size_t)(tok0 + wv * 32 + m * 16 + r) * 6144 + h * 64 + kc * 32 + g * 8];
  __syncthreads();

  float rs[2][4] = {};
  for (int n = 0; n < 16; ++n) {
    const int srow = n * 16 + r;
    short8 kf0 = *(const short8*)&Ks[srow * 64 + ((g) ^ (srow & 7)) * 8];
    short8 kf1 = *(const short8*)&Ks[srow * 64 + ((4 + g) ^ (srow & 7)) * 8];
#pragma unroll
    for (int m = 0; m < 2; ++m) {
      f32x4 acc = {0.f, 0.f, 0.f, 0.f};
      acc = mfma16(qf[m][0], kf0, acc);
      acc = mfma16(qf[m][1], kf1, acc);
#pragma unroll
      for (int i = 0; i < 4; ++i) {
        int rr = wv * 32 + m * 16 + g * 4 + i;
        int ss = n * 16 + r;
        bool valid = (ss >= rr + 1) && (ss <= rr + 128) && (qb > 0 || ss >= 128);
        float p = valid ? __expf(acc[i] * 0.125f) : 0.f;  // scores small: no max-sub needed
        rs[m][i] += p;
        Ps[rr * 264 + ss] = f2b(p);
      }
    }
  }
#pragma unroll
  for (int m = 0; m < 2; ++m)
#pragma unroll
    for (int i = 0; i < 4; ++i) {
      float v = rs[m][i];
      v += __shfl_xor(v, 1); v += __shfl_xor(v, 2);
      v += __shfl_xor(v, 4); v += __shfl_xor(v, 8);
      if (r == i) dn[wv * 32 + m * 16 + g * 4 + i] = v;
    }
  __syncthreads();

  f32x4 oacc[2][4] = {};
  for (int sc = 0; sc < 8; ++sc) {
    short8 pf[2], vf[4];
#pragma unroll
    for (int m = 0; m < 2; ++m)
      pf[m] = *(const short8*)&Ps[(wv * 32 + m * 16 + r) * 264 + sc * 32 + g * 8];
#pragma unroll
    for (int n = 0; n < 4; ++n)
      vf[n] = *(const short8*)&Vt[(n * 16 + r) * 264 + sc * 32 + g * 8];
#pragma unroll
    for (int m = 0; m < 2; ++m)
#pragma unroll
      for (int n = 0; n < 4; ++n)
        oacc[m][n] = mfma16(pf[m], vf[n], oacc[m][n]);
  }
#pragma unroll
  for (int m = 0; m < 2; ++m) {
    f32x4 dv = *(const f32x4*)&dn[wv * 32 + m * 16 + g * 4];
#pragma unroll
    for (int n = 0; n < 4; ++n) {
      int col = h * 64 + n * 16 + r;
#pragma unroll
      for (int i = 0; i < 4; ++i) {
        size_t row = (size_t)(tok0 + wv * 32 + m * 16 + g * 4 + i);
        outc[row * 2048 + col] = f2b(oacc[m][n][i] / dv[i]);
      }
    }
  }
}

// ---------------- Linear attention pass 1: per-chunk KVt[f][e], kz[e] ----------------
// qkv points at the S-half (fused buffer + 3072), row stride 6144.
__global__ __launch_bounds__(256) void lin_pass1(
    const unsigned short* __restrict__ qkv, float* __restrict__ KVt, float* __restrict__ kz) {
  __shared__ __attribute__((aligned(16))) unsigned short kf[128 * 72];
  __shared__ __attribute__((aligned(16))) unsigned short vs[128 * 72];
  const int bid = blockIdx.x;
  const int ch = bid & 31, h = (bid >> 5) & 15, b = bid >> 9;
  const size_t tok0 = (size_t)b * 4096 + (size_t)ch * 128;
  const int tid = threadIdx.x;
#pragma unroll
  for (int i = 0; i < 4; ++i) {
    int c = i * 256 + tid;
    int row = c >> 3, e8 = c & 7;
    u16x8 uk = *(const u16x8*)&qkv[(tok0 + row) * 6144 + 1024 + h * 64 + e8 * 8];
    u16x8 uv = *(const u16x8*)&qkv[(tok0 + row) * 6144 + 2048 + h * 64 + e8 * 8];
    u16x8 tk;
#pragma unroll
    for (int j = 0; j < 8; ++j) {
      float x = b2f(uk[j]);
      x = (x > 0.f) ? x : expm1f(x);  // elu
      tk[j] = f2b(x + 1.0001f);
    }
    *(u16x8*)&kf[row * 72 + e8 * 8] = tk;
    *(u16x8*)&vs[row * 72 + e8 * 8] = uv;
  }
  __syncthreads();
  const int e0 = (tid & 15) * 4, f0 = (tid >> 4) * 4;
  float acc[4][4] = {};
  for (int c = 0; c < 128; ++c) {
    u16x4 ku = *(const u16x4*)&kf[c * 72 + e0];
    u16x4 vu = *(const u16x4*)&vs[c * 72 + f0];
    float ke[4], vv[4];
#pragma unroll
    for (int j = 0; j < 4; ++j) { ke[j] = b2f(ku[j]); vv[j] = b2f(vu[j]); }
#pragma unroll
    for (int jf = 0; jf < 4; ++jf)
#pragma unroll
      for (int je = 0; je < 4; ++je)
        acc[jf][je] += vv[jf] * ke[je];
  }
  const size_t base = (size_t)bid * 4096;
#pragma unroll
  for (int jf = 0; jf < 4; ++jf) {
    f32x4 o = {acc[jf][0], acc[jf][1], acc[jf][2], acc[jf][3]};
    *(f32x4*)&KVt[base + (f0 + jf) * 64 + e0] = o;
  }
  if (tid < 64) {
    float s = 0.f;
    for (int c = 0; c < 128; ++c) s += b2f(kf[c * 72 + tid]);
    kz[(size_t)bid * 64 + tid] = s;
  }
}

// ---------------- pass 2: per (b,h) exclusive prefix over 32 chunks (in place) -------------
// Parallelized: 128 blocks = 32 bh x 4 slices (was 32 blocks = 1/8 of the CUs). Each thread
// owns one f32x4 chain of length 32; element coverage and per-chain order identical to the
// old version -> bit-identical results. Slice 0 also handles the 64-wide kz chains.
__global__ __launch_bounds__(256) void lin_pass2(float* __restrict__ KVt, float* __restrict__ kz) {
  const int bh = blockIdx.x >> 2, sl = blockIdx.x & 3;
  const int tid = threadIdx.x;
  const size_t eo = (size_t)(sl * 256 + tid) * 4;
  f32x4 run = {0.f, 0.f, 0.f, 0.f};
  for (int ch = 0; ch < 32; ++ch) {
    float* p = &KVt[((size_t)bh * 32 + ch) * 4096 + eo];
    f32x4 c = *(f32x4*)p;
    *(f32x4*)p = run;
    run += c;
  }
  if (sl == 0 && tid < 64) {
    float rz = 0.f;
    for (int ch = 0; ch < 32; ++ch) {
      float* p = &kz[((size_t)bh * 32 + ch) * 64 + tid];
      float c = *p; *p = rz; rz += c;
    }
  }
}

// ---------------- pass 3: o = (q@S_prev + tril(qk^T)@v) / (q.z_prev + rowsumA + 1e-6) ----------------
__global__ __launch_bounds__(256) void lin_pass3(
    const unsigned short* __restrict__ qkv, const float* __restrict__ KVt,
    const float* __restrict__ kz, unsigned short* __restrict__ outc) {
  __shared__ __attribute__((aligned(16))) unsigned short qf[128 * 72];
  __shared__ __attribute__((aligned(16))) unsigned short kf[128 * 72];
  __shared__ __attribute__((aligned(16))) unsigned short vt[64 * 136];
  __shared__ __attribute__((aligned(16))) unsigned short st[64 * 72];
  __shared__ __attribute__((aligned(16))) unsigned short am[128 * 136];
  __shared__ __attribute__((aligned(16))) float zs[64];
  __shared__ __attribute__((aligned(16))) float dnl[128];
  const int bid = blockIdx.x;
  const int ch = bid & 31, h = (bid >> 5) & 15, b = bid >> 9;
  const size_t tok0 = (size_t)b * 4096 + (size_t)ch * 128;
  const int tid = threadIdx.x, lane = tid & 63, wv = tid >> 6;
  const int g = lane >> 4, r = lane & 15;

#pragma unroll
  for (int i = 0; i < 4; ++i) {
    int c = i * 256 + tid;
    int row = c >> 3, e8 = c & 7;
    u16x8 uq = *(const u16x8*)&qkv[(tok0 + row) * 6144 + h * 64 + e8 * 8];
    u16x8 uk = *(const u16x8*)&qkv[(tok0 + row) * 6144 + 1024 + h * 64 + e8 * 8];
    u16x8 uv = *(const u16x8*)&qkv[(tok0 + row) * 6144 + 2048 + h * 64 + e8 * 8];
    u16x8 tq, tk;
#pragma unroll
    for (int j = 0; j < 8; ++j) {
      float x = b2f(uq[j]) * 0.125f;
      x = (x > 0.f) ? x : expm1f(x);
      tq[j] = f2b(x + 1.0001f);
      float y = b2f(uk[j]);
      y = (y > 0.f) ? y : expm1f(y);
      tk[j] = f2b(y + 1.0001f);
    }
    *(u16x8*)&qf[row * 72 + e8 * 8] = tq;
    *(u16x8*)&kf[row * 72 + e8 * 8] = tk;
#pragma unroll
    for (int j = 0; j < 8; ++j) vt[(e8 * 8 + j) * 136 + row] = uv[j];
  }
#pragma unroll
  for (int i = 0; i < 2; ++i) {  // S_prev^T (f-major) f32 -> bf16 LDS
    int idx = i * 256 + tid;
    int f = idx >> 3, e8 = idx & 7;
    f32x4 s0 = *(const f32x4*)&KVt[(size_t)bid * 4096 + f * 64 + e8 * 8];
    f32x4 s1 = *(const f32x4*)&KVt[(size_t)bid * 4096 + f * 64 + e8 * 8 + 4];
    u16x8 t;
#pragma unroll
    for (int j = 0; j < 4; ++j) { t[j] = f2b(s0[j]); t[4 + j] = f2b(s1[j]); }
    *(u16x8*)&st[f * 72 + e8 * 8] = t;
  }
  if (tid < 64) zs[tid] = kz[(size_t)bid * 64 + tid];
  __syncthreads();

  short8 aq[2][2];
#pragma unroll
  for (int m = 0; m < 2; ++m)
#pragma unroll
    for (int kc = 0; kc < 2; ++kc)
      aq[m][kc] = *(const short8*)&qf[(wv * 32 + m * 16 + r) * 72 + kc * 32 + g * 8];

  float rsA[2][4] = {};
  for (int n = 0; n < 8; ++n) {  // A = tril(qf @ kf^T), bf16 to LDS + rowsums
    short8 bk0 = *(const short8*)&kf[(n * 16 + r) * 72 + g * 8];
    short8 bk1 = *(const short8*)&kf[(n * 16 + r) * 72 + 32 + g * 8];
#pragma unroll
    for (int m = 0; m < 2; ++m) {
      f32x4 acc = {0.f, 0.f, 0.f, 0.f};
      acc = mfma16(aq[m][0], bk0, acc);
      acc = mfma16(aq[m][1], bk1, acc);
#pragma unroll
      for (int i = 0; i < 4; ++i) {
        int rr = wv * 32 + m * 16 + g * 4 + i;
        int cc = n * 16 + r;
        float v = (cc <= rr) ? acc[i] : 0.f;
        rsA[m][i] += v;
        am[rr * 136 + cc] = f2b(v);
      }
    }
  }
#pragma unroll
  for (int m = 0; m < 2; ++m)
#pragma unroll
    for (int i = 0; i < 4; ++i) {
      float v = rsA[m][i];
      v += __shfl_xor(v, 1); v += __shfl_xor(v, 2);
      v += __shfl_xor(v, 4); v += __shfl_xor(v, 8);
      if (r == i) dnl[wv * 32 + m * 16 + g * 4 + i] = v;
    }
  __syncthreads();

  if (tid < 128) {  // den = rowsumA + qf . z_prev
    float s = dnl[tid];
#pragma unroll
    for (int e = 0; e < 64; e += 4) {
      u16x4 qv = *(const u16x4*)&qf[tid * 72 + e];
      s += b2f(qv[0]) * zs[e] + b2f(qv[1]) * zs[e + 1] + b2f(qv[2]) * zs[e + 2] + b2f(qv[3]) * zs[e + 3];
    }
    dnl[tid] = s + 1e-6f;
  }

  f32x4 oac[2][4] = {};
#pragma unroll
  for (int kc = 0; kc < 2; ++kc) {  // num += qf @ S_prev
    short8 sf[4];
#pragma unroll
    for (int n = 0; n < 4; ++n) sf[n] = *(const short8*)&st[(n * 16 + r) * 72 + kc * 32 + g * 8];
#pragma unroll
    for (int m = 0; m < 2; ++m)
#pragma unroll
      for (int n = 0; n < 4; ++n)
        oac[m][n] = mfma16(aq[m][kc], sf[n], oac[m][n]);
  }
  for (int c4 = 0; c4 < 4; ++c4) {  // num += A @ v
    short8 pa[2], vb[4];
#pragma unroll
    for (int m = 0; m < 2; ++m)
      pa[m] = *(const short8*)&am[(wv * 32 + m * 16 + r) * 136 + c4 * 32 + g * 8];
#pragma unroll
    for (int n = 0; n < 4; ++n)
      vb[n] = *(const short8*)&vt[(n * 16 + r) * 136 + c4 * 32 + g * 8];
#pragma unroll
    for (int m = 0; m < 2; ++m)
#pragma unroll
      for (int n = 0; n < 4; ++n)
        oac[m][n] = mfma16(pa[m], vb[n], oac[m][n]);
  }
  __syncthreads();
#pragma unroll
  for (int m = 0; m < 2; ++m) {
    f32x4 dv = *(const f32x4*)&dnl[wv * 32 + m * 16 + g * 4];
#pragma unroll
    for (int n = 0; n < 4; ++n) {
      int col = 1024 + h * 64 + n * 16 + r;
#pragma unroll
      for (int i = 0; i < 4; ++i) {
        size_t row = tok0 + wv * 32 + m * 16 + g * 4 + i;
        outc[row * 2048 + col] = f2b(oac[m][n][i] / dv[i]);
      }
    }
  }
}

// ---------------- host ----------------
extern "C" void kernel_launch(void* const* d_in, const int* in_sizes, int n_in,
                              void* d_out, int out_size, void* d_ws, size_t ws_size,
                              hipStream_t stream) {
  (void)in_sizes; (void)n_in; (void)out_size; (void)ws_size;
  const float* x      = (const float*)d_in[0];
  const float* g1     = (const float*)d_in[1];
  const float* b1     = (const float*)d_in[2];
  const float* Wqkv_a = (const float*)d_in[3];
  const float* bqkv_a = (const float*)d_in[4];
  const float* Wp_a   = (const float*)d_in[5];
  const float* bp_a   = (const float*)d_in[6];
  const float* Wqkv_s = (const float*)d_in[7];
  const float* bqkv_s = (const float*)d_in[8];
  const float* Wo_s   = (const float*)d_in[9];
  const float* bo_s   = (const float*)d_in[10];
  const float* Wo     = (const float*)d_in[11];
  const float* bo     = (const float*)d_in[12];
  const float* gm     = (const float*)d_in[13];
  const float* bm     = (const float*)d_in[14];
  const float* W1     = (const float*)d_in[15];
  const float* b1m    = (const float*)d_in[16];
  const float* W2     = (const float*)d_in[17];
  const float* b2m    = (const float*)d_in[18];
  float* out = (float*)d_out;

  char* ws = (char*)d_ws;
  size_t off = 0;
  auto alloc = [&](size_t bytes) { char* p = ws + off; off += (bytes + 255) & ~(size_t)255; return p; };
  unsigned short* wTaS  = (unsigned short*)alloc((size_t)6144 * 1024 * 2);  // [Wqkv_a^T ; Wqkv_s^T]
  unsigned short* wTpo  = (unsigned short*)alloc((size_t)1024 * 2048 * 2);
  unsigned short* wTo   = (unsigned short*)alloc((size_t)1024 * 1024 * 2);
  unsigned short* wT1   = (unsigned short*)alloc((size_t)4096 * 1024 * 2);
  unsigned short* wT2   = (unsigned short*)alloc((size_t)1024 * 4096 * 2);
  float*          bcomb = (float*)alloc(1024 * 4);
  float*          bcat  = (float*)alloc(6144 * 4);
  unsigned short* xn    = (unsigned short*)alloc((size_t)8192 * 1024 * 2);  // reused as h
  unsigned short* qkvAS = (unsigned short*)alloc((size_t)8192 * 6144 * 2);  // fused; reused as gbuf
  unsigned short* comb  = (unsigned short*)alloc((size_t)8192 * 2048 * 2);  // reused as x1 (f32)
  float*          kvt   = (float*)alloc((size_t)1024 * 4096 * 4);           // reused as sum (bf16)
  float*          kzp   = (float*)alloc((size_t)1024 * 64 * 4);
  unsigned short* gbuf  = qkvAS;
  unsigned short* sum   = (unsigned short*)kvt;
  unsigned short* h_    = xn;
  float*          x1    = (float*)comb;  // comb dead once sum is computed

  // one batched dispatch for all 7 weight transposes
  TW7 tw;
  tw.S[0] = Wqkv_a; tw.D[0] = wTaS;                         tw.N[0] = 3072; tw.dld[0] = 1024; tw.doff[0] = 0;    tw.gx[0] = 16;
  tw.S[1] = Wqkv_s; tw.D[1] = wTaS + (size_t)3072 * 1024;   tw.N[1] = 3072; tw.dld[1] = 1024; tw.doff[1] = 0;    tw.gx[1] = 16;
  tw.S[2] = Wp_a;   tw.D[2] = wTpo;                         tw.N[2] = 1024; tw.dld[2] = 2048; tw.doff[2] = 0;    tw.gx[2] = 16;
  tw.S[3] = Wo_s;   tw.D[3] = wTpo;                         tw.N[3] = 1024; tw.dld[3] = 2048; tw.doff[3] = 1024; tw.gx[3] = 16;
  tw.S[4] = Wo;     tw.D[4] = wTo;                          tw.N[4] = 1024; tw.dld[4] = 1024; tw.doff[4] = 0;    tw.gx[4] = 16;
  tw.S[5] = W1;     tw.D[5] = wT1;                          tw.N[5] = 4096; tw.dld[5] = 1024; tw.doff[5] = 0;    tw.gx[5] = 16;
  tw.S[6] = W2;     tw.D[6] = wT2;                          tw.N[6] = 1024; tw.dld[6] = 4096; tw.doff[6] = 0;    tw.gx[6] = 64;
  tw.start[0] = 0;    tw.start[1] = 768;  tw.start[2] = 1536; tw.start[3] = 1792;
  tw.start[4] = 2048; tw.start[5] = 2304; tw.start[6] = 3328; tw.start[7] = 4352;
  transpose_w7<<<4352, 256, 0, stream>>>(tw);
  bias_comb<<<4, 256, 0, stream>>>(bp_a, bo_s, bcomb);
  bias_cat<<<24, 256, 0, stream>>>(bqkv_a, bqkv_s, bcat, 3072);

  ln_kernel<<<8192, 256, 0, stream>>>(x, g1, b1, xn);
  // fused QKV: M=8192, N=6144, K=1024 -> big 256x256, grid 32x24
  gemm_big<EPI_STORE, 0><<<dim3(32, 24), 512, 0, stream>>>(xn, wTaS, bcat, qkvAS, nullptr, 1024, 1024, 6144);
  swa_kernel<<<1024, 256, 0, stream>>>(qkvAS, comb);
  lin_pass1<<<1024, 256, 0, stream>>>(qkvAS + 3072, kvt, kzp);
  lin_pass2<<<128, 256, 0, stream>>>(kvt, kzp);
  lin_pass3<<<1024, 256, 0, stream>>>(qkvAS + 3072, kvt, kzp, comb);
  // sum = [attn|ssm] @ [Wp_a;Wo_s] + (bp_a+bo_s): M=8192,N=1024,K=2048 -> small, grid 64x4
  gemm_sml<EPI_STORE, 0><<<dim3(64, 4), 512, 0, stream>>>(comb, wTpo, bcomb, sum, nullptr, 2048, 2048, 1024);
  // x1 = x + sum @ Wo + bo (f32 out): M=8192,N=1024,K=1024
  gemm_sml<EPI_RES, 1><<<dim3(64, 4), 512, 0, stream>>>(sum, wTo, bo, x1, x, 1024, 1024, 1024);
  ln_kernel<<<8192, 256, 0, stream>>>(x1, gm, bm, h_);
  // MLP1: M=8192,N=4096,K=1024 -> big, grid 32x16
  gemm_big<EPI_GELU, 0><<<dim3(32, 16), 512, 0, stream>>>(h_, wT1, b1m, gbuf, nullptr, 1024, 1024, 4096);
  // MLP2: M=8192,N=1024,K=4096 -> small, grid 64x4
  gemm_sml<EPI_RES, 1><<<dim3(64, 4), 512, 0, stream>>>(gbuf, wT2, b2m, out, x1, 4096, 4096, 1024);
}

// Round 13
// 566.219 us; speedup vs baseline: 1.2648x; 1.0410x over previous
//
#include <hip/hip_runtime.h>
#include <hip/hip_bf16.h>
#include <math.h>

typedef __hip_bfloat16 bf16;
typedef float f32x4 __attribute__((ext_vector_type(4)));
typedef short short8 __attribute__((ext_vector_type(8)));
typedef unsigned short u16x4 __attribute__((ext_vector_type(4)));
typedef unsigned short u16x8 __attribute__((ext_vector_type(8)));

#define AS1 __attribute__((address_space(1)))
#define AS3 __attribute__((address_space(3)))

__device__ __forceinline__ void gload16(const void* g, void* l) {
  __builtin_amdgcn_global_load_lds((const AS1 unsigned int*)g, (AS3 unsigned int*)l, 16, 0, 0);
}
__device__ __forceinline__ float b2f(unsigned short u) {
  union { unsigned int i; float f; } c; c.i = ((unsigned int)u) << 16; return c.f;
}
__device__ __forceinline__ unsigned short f2b(float f) {
  bf16 h = __float2bfloat16(f);
  unsigned short s; __builtin_memcpy(&s, &h, 2); return s;
}
__device__ __forceinline__ f32x4 mfma16(short8 a, short8 b, f32x4 c) {
  return __builtin_amdgcn_mfma_f32_16x16x32_bf16(a, b, c, 0, 0, 0);
}
// fast ELU: result is rounded to bf16 immediately after, so __expf's ~2-ulp error
// (abs ~1e-7 here) is invisible vs expm1f; avoids the slow libm polynomial.
__device__ __forceinline__ float elu_fast(float x) {
  return (x > 0.f) ? x : (__expf(x) - 1.f);
}

#define BARR asm volatile("s_barrier" ::: "memory")
#define LGKM0 asm volatile("s_waitcnt lgkmcnt(0)" ::: "memory")
#define VM8 asm volatile("s_waitcnt vmcnt(8)" ::: "memory")
#define VM6 asm volatile("s_waitcnt vmcnt(6)" ::: "memory")
#define VM4 asm volatile("s_waitcnt vmcnt(4)" ::: "memory")
#define VM3 asm volatile("s_waitcnt vmcnt(3)" ::: "memory")
#define VM0 asm volatile("s_waitcnt vmcnt(0)" ::: "memory")
#define SB0 __builtin_amdgcn_sched_barrier(0)
#define PRIO1 __builtin_amdgcn_s_setprio(1)
#define PRIO0 __builtin_amdgcn_s_setprio(0)

// ---------------- LayerNorm: f32 in -> bf16 out, one block per 1024-wide row ----------------
__global__ __launch_bounds__(256) void ln_kernel(
    const float* __restrict__ X, const float* __restrict__ G,
    const float* __restrict__ Bb, unsigned short* __restrict__ Y) {
  __shared__ float red[8];
  const size_t row = blockIdx.x;
  const int tid = threadIdx.x;
  f32x4 v = *(const f32x4*)&X[row * 1024 + tid * 4];
  float s = 0.f, sq = 0.f;
#pragma unroll
  for (int j = 0; j < 4; ++j) { s += v[j]; sq += v[j] * v[j]; }
#pragma unroll
  for (int o = 1; o < 64; o <<= 1) { s += __shfl_xor(s, o); sq += __shfl_xor(sq, o); }
  if ((tid & 63) == 0) { red[tid >> 6] = s; red[4 + (tid >> 6)] = sq; }
  __syncthreads();
  s = red[0] + red[1] + red[2] + red[3];
  sq = red[4] + red[5] + red[6] + red[7];
  const float mean = s * (1.f / 1024.f);
  const float var = sq * (1.f / 1024.f) - mean * mean;
  const float inv = 1.f / sqrtf(var + 1e-5f);
  f32x4 gv = *(const f32x4*)&G[tid * 4];
  f32x4 bv = *(const f32x4*)&Bb[tid * 4];
  u16x4 ov;
#pragma unroll
  for (int j = 0; j < 4; ++j) ov[j] = f2b((v[j] - mean) * inv * gv[j] + bv[j]);
  *(u16x4*)&Y[row * 1024 + tid * 4] = ov;
}

// ---------------- Batched weight transpose: 7 transposes in ONE dispatch ----------------
struct TW7 {
  const float* S[7];
  unsigned short* D[7];
  int N[7], dld[7], doff[7], gx[7];
  int start[8];
};
__global__ __launch_bounds__(256) void transpose_w7(TW7 tw) {
  __shared__ __attribute__((aligned(16))) unsigned short t[64][72];
  const int bid = blockIdx.x;
  int c = 0;
#pragma unroll
  for (int j = 0; j < 7; ++j)
    if (bid >= tw.start[j]) c = j;
  const int local = bid - tw.start[c];
  const int k0 = (local % tw.gx[c]) * 64, n0 = (local / tw.gx[c]) * 64;
  const float* S = tw.S[c];
  unsigned short* D = tw.D[c];
  const int N = tw.N[c], dld = tw.dld[c], doff = tw.doff[c];
  const int tid = threadIdx.x;
#pragma unroll
  for (int i = 0; i < 2; ++i) {
    int cc = i * 256 + tid;
    int row = cc >> 3, c8 = cc & 7;
    f32x4 a = *(const f32x4*)&S[(size_t)(k0 + row) * N + n0 + c8 * 8];
    f32x4 b = *(const f32x4*)&S[(size_t)(k0 + row) * N + n0 + c8 * 8 + 4];
    u16x8 o;
#pragma unroll
    for (int j = 0; j < 4; ++j) { o[j] = f2b(a[j]); o[4 + j] = f2b(b[j]); }
    *(u16x8*)&t[row][c8 * 8] = o;
  }
  __syncthreads();
#pragma unroll
  for (int i = 0; i < 2; ++i) {
    int cc = i * 256 + tid;
    int nrow = cc >> 3, k8 = cc & 7;
    u16x8 o;
#pragma unroll
    for (int j = 0; j < 8; ++j) o[j] = t[k8 * 8 + j][nrow];
    *(u16x8*)&D[(size_t)(n0 + nrow) * dld + doff + k0 + k8 * 8] = o;
  }
}

// ---------------- bias prep: bcomb = bp_a+bo_s (1024) | bcat = bqkv_a|bqkv_s (6144) --------
__global__ __launch_bounds__(256) void bias_prep(
    const float* __restrict__ bp_a, const float* __restrict__ bo_s,
    const float* __restrict__ bqkv_a, const float* __restrict__ bqkv_s,
    float* __restrict__ bcomb, float* __restrict__ bcat) {
  int i = blockIdx.x * 256 + threadIdx.x;
  if (i < 1024) {
    bcomb[i] = bp_a[i] + bo_s[i];
  } else {
    int j = i - 1024;
    bcat[j] = (j < 3072) ? bqkv_a[j] : bqkv_s[j - 3072];
  }
}

#define EPI_STORE 0
#define EPI_GELU 1
#define EPI_RES 2

// ---------------- GEMM big: 256x256, BK=64, DEEP counted-vmcnt (lead-3), 2x32 MFMA --------
// Best-measured GEMM config (R10/R11). Structural plateau — do not touch.
template <int EPI, int OF32>
__global__ __launch_bounds__(512, 2) void gemm_big(
    const unsigned short* __restrict__ A, const unsigned short* __restrict__ Bt,
    const float* __restrict__ bias, void* __restrict__ Cv,
    const float* __restrict__ res, int K, int ldA, int ldC) {
  __shared__ __attribute__((aligned(16))) unsigned short Abuf[2][2][16 * 512];
  __shared__ __attribute__((aligned(16))) unsigned short Bbuf[2][2][16 * 512];
  const int tid = threadIdx.x, lane = tid & 63, wv = tid >> 6;
  const int g = lane >> 4, r = lane & 15;
  const int wr = wv >> 2, wc = wv & 3;
  const size_t arow0 = (size_t)blockIdx.x * 256;
  const size_t brow0 = (size_t)blockIdx.y * 256;
  const size_t ldAs = (size_t)ldA, Ksz = (size_t)K;
  const unsigned short* gA0 = A + (arow0 + (size_t)((2 * wv + 0) * 16 + r)) * ldAs + g * 8;
  const unsigned short* gA1 = A + (arow0 + (size_t)((2 * wv + 1) * 16 + r)) * ldAs + g * 8;
  const unsigned short* gB0 = Bt + (brow0 + (size_t)((2 * wv + 0) * 16 + r)) * Ksz + g * 8;
  const unsigned short* gB1 = Bt + (brow0 + (size_t)((2 * wv + 1) * 16 + r)) * Ksz + g * 8;
  const int nT = K >> 6;
  f32x4 acc[8][4] = {};
  short8 af[8], bfr[4];

#define STG(BUF, KK, T_) do { size_t o_ = (size_t)(T_) * 64 + (KK) * 32;            \
    gload16(gA0 + o_, &Abuf[BUF][KK][(2 * wv + 0) * 512]);                           \
    gload16(gA1 + o_, &Abuf[BUF][KK][(2 * wv + 1) * 512]);                           \
    gload16(gB0 + o_, &Bbuf[BUF][KK][(2 * wv + 0) * 512]);                           \
    gload16(gB1 + o_, &Bbuf[BUF][KK][(2 * wv + 1) * 512]); } while (0)
#define RDF(CUR, KK) do {                                                            \
    _Pragma("unroll") for (int m_ = 0; m_ < 8; ++m_)                                 \
      af[m_] = *(const short8*)&Abuf[CUR][KK][(wr * 8 + m_) * 512 + lane * 8];       \
    _Pragma("unroll") for (int n_ = 0; n_ < 4; ++n_)                                 \
      bfr[n_] = *(const short8*)&Bbuf[CUR][KK][(wc * 4 + n_) * 512 + lane * 8]; } while (0)
#define MMQ() _Pragma("unroll") for (int m_ = 0; m_ < 8; ++m_)                       \
    _Pragma("unroll") for (int n_ = 0; n_ < 4; ++n_)                                 \
      acc[m_][n_] = mfma16(af[m_], bfr[n_], acc[m_][n_]);

  STG(0, 0, 0); STG(0, 1, 0); STG(1, 0, 1);
  VM8; BARR; SB0;

  for (int T = 0; T < nT; ++T) {
    const int cur = T & 1;
    RDF(cur, 0);
    if (T + 1 < nT) STG(cur ^ 1, 1, T + 1);
    BARR; LGKM0; SB0;
    PRIO1; MMQ(); PRIO0;
    if (T + 1 < nT) { VM8; } else { VM0; }
    BARR; SB0;
    RDF(cur, 1);
    if (T + 2 < nT) STG(cur, 0, T + 2);
    BARR; LGKM0; SB0;
    PRIO1; MMQ(); PRIO0;
    if (T + 2 < nT) { VM8; } else if (T + 1 < nT) { VM4; }
    BARR; SB0;
  }
#undef STG
#undef RDF
#undef MMQ

#pragma unroll
  for (int m = 0; m < 8; ++m) {
#pragma unroll
    for (int n = 0; n < 4; ++n) {
      const int col = (int)brow0 + wc * 64 + n * 16 + r;
      const float bv = bias[col];
#pragma unroll
      for (int i = 0; i < 4; ++i) {
        const size_t row = arow0 + wr * 128 + m * 16 + g * 4 + i;
        float v = acc[m][n][i] + bv;
        if (EPI == EPI_GELU) v = 0.5f * v * (1.f + erff(v * 0.70710678118f));
        if (EPI == EPI_RES) v += res[row * ldC + col];
        if (OF32) ((float*)Cv)[row * ldC + col] = v;
        else ((unsigned short*)Cv)[row * ldC + col] = f2b(v);
      }
    }
  }
}

// ---------------- GEMM small: 128x256, BK=64, DEEP counted-vmcnt (lead-3) -----------------
template <int EPI, int OF32>
__global__ __launch_bounds__(512, 2) void gemm_sml(
    const unsigned short* __restrict__ A, const unsigned short* __restrict__ Bt,
    const float* __restrict__ bias, void* __restrict__ Cv,
    const float* __restrict__ res, int K, int ldA, int ldC) {
  __shared__ __attribute__((aligned(16))) unsigned short Abuf[2][2][8 * 512];
  __shared__ __attribute__((aligned(16))) unsigned short Bbuf[2][2][16 * 512];
  const int tid = threadIdx.x, lane = tid & 63, wv = tid >> 6;
  const int g = lane >> 4, r = lane & 15;
  const int wr = wv >> 2, wc = wv & 3;
  const size_t arow0 = (size_t)blockIdx.x * 128;
  const size_t brow0 = (size_t)blockIdx.y * 256;
  const size_t ldAs = (size_t)ldA, Ksz = (size_t)K;
  const unsigned short* gAs = A + (arow0 + (size_t)(wv * 16 + r)) * ldAs + g * 8;
  const unsigned short* gB0 = Bt + (brow0 + (size_t)((2 * wv + 0) * 16 + r)) * Ksz + g * 8;
  const unsigned short* gB1 = Bt + (brow0 + (size_t)((2 * wv + 1) * 16 + r)) * Ksz + g * 8;
  const int nT = K >> 6;
  f32x4 acc[4][4] = {};
  short8 af[4], bfr[4];

#define STG(BUF, KK, T_) do { size_t o_ = (size_t)(T_) * 64 + (KK) * 32;            \
    gload16(gAs + o_, &Abuf[BUF][KK][wv * 512]);                                     \
    gload16(gB0 + o_, &Bbuf[BUF][KK][(2 * wv + 0) * 512]);                           \
    gload16(gB1 + o_, &Bbuf[BUF][KK][(2 * wv + 1) * 512]); } while (0)
#define RDF(CUR, KK) do {                                                            \
    _Pragma("unroll") for (int m_ = 0; m_ < 4; ++m_)                                 \
      af[m_] = *(const short8*)&Abuf[CUR][KK][(wr * 4 + m_) * 512 + lane * 8];       \
    _Pragma("unroll") for (int n_ = 0; n_ < 4; ++n_)                                 \
      bfr[n_] = *(const short8*)&Bbuf[CUR][KK][(wc * 4 + n_) * 512 + lane * 8]; } while (0)
#define MMQ() _Pragma("unroll") for (int m_ = 0; m_ < 4; ++m_)                       \
    _Pragma("unroll") for (int n_ = 0; n_ < 4; ++n_)                                 \
      acc[m_][n_] = mfma16(af[m_], bfr[n_], acc[m_][n_]);

  STG(0, 0, 0); STG(0, 1, 0); STG(1, 0, 1);
  VM6; BARR; SB0;

  for (int T = 0; T < nT; ++T) {
    const int cur = T & 1;
    RDF(cur, 0);
    if (T + 1 < nT) STG(cur ^ 1, 1, T + 1);
    BARR; LGKM0; SB0;
    PRIO1; MMQ(); PRIO0;
    if (T + 1 < nT) { VM6; } else { VM0; }
    BARR; SB0;
    RDF(cur, 1);
    if (T + 2 < nT) STG(cur, 0, T + 2);
    BARR; LGKM0; SB0;
    PRIO1; MMQ(); PRIO0;
    if (T + 2 < nT) { VM6; } else if (T + 1 < nT) { VM3; }
    BARR; SB0;
  }
#undef STG
#undef RDF
#undef MMQ

#pragma unroll
  for (int m = 0; m < 4; ++m) {
#pragma unroll
    for (int n = 0; n < 4; ++n) {
      const int col = (int)brow0 + wc * 64 + n * 16 + r;
      const float bv = bias[col];
#pragma unroll
      for (int i = 0; i < 4; ++i) {
        const size_t row = arow0 + wr * 64 + m * 16 + g * 4 + i;
        float v = acc[m][n][i] + bv;
        if (EPI == EPI_GELU) v = 0.5f * v * (1.f + erff(v * 0.70710678118f));
        if (EPI == EPI_RES) v += res[row * ldC + col];
        if (OF32) ((float*)Cv)[row * ldC + col] = v;
        else ((unsigned short*)Cv)[row * ldC + col] = f2b(v);
      }
    }
  }
}

// ---------------- Sliding-window attention: one wg per (b,h,qblock of 128) ----------------
__global__ __launch_bounds__(256) void swa_kernel(
    const unsigned short* __restrict__ qkv, unsigned short* __restrict__ outc) {
  __shared__ __attribute__((aligned(16))) unsigned short Ks[256 * 64];   // swizzled [s][e]
  __shared__ __attribute__((aligned(16))) unsigned short Vt[64 * 264];   // [e][s]
  __shared__ __attribute__((aligned(16))) unsigned short Ps[128 * 264];  // [r][s]
  __shared__ __attribute__((aligned(16))) float dn[128];
  const int bid = blockIdx.x;
  const int qb = bid & 31, h = (bid >> 5) & 15, b = bid >> 9;
  const long btok = (long)b * 4096;
  const long tok0 = btok + (long)qb * 128;
  const int tid = threadIdx.x, lane = tid & 63, wv = tid >> 6;
  const int g = lane >> 4, r = lane & 15;

#pragma unroll
  for (int i = 0; i < 8; ++i) {  // K stage: 16B chunks, chunk-XOR swizzle over 8 chunks/row
    int chunk = (wv * 8 + i) * 64 + lane;
    int s = chunk >> 3, cc = (chunk & 7) ^ (s & 7);
    long kt = tok0 - 128 + s; if (kt < btok) kt = btok;  // block 0: masked anyway
    gload16(&qkv[(size_t)kt * 6144 + 1024 + h * 64 + cc * 8], &Ks[(wv * 8 + i) * 512]);
  }
#pragma unroll
  for (int i = 0; i < 8; ++i) {  // V transposed stage
    int chunk = i * 256 + tid;
    int s = chunk >> 3, e8 = chunk & 7;
    long kt = tok0 - 128 + s; if (kt < btok) kt = btok;
    u16x8 u = *(const u16x8*)&qkv[(size_t)kt * 6144 + 2048 + h * 64 + e8 * 8];
#pragma unroll
    for (int j = 0; j < 8; ++j) Vt[(e8 * 8 + j) * 264 + s] = u[j];
  }
  short8 qf[2][2];  // Q frags direct from global
#pragma unroll
  for (int m = 0; m < 2; ++m)
#pragma unroll
    for (int kc = 0; kc < 2; ++kc)
      qf[m][kc] = *(const short8*)&qkv[(size_t)(tok0 + wv * 32 + m * 16 + r) * 6144 + h * 64 + kc * 32 + g * 8];
  __syncthreads();

  float rs[2][4] = {};
  for (int n = 0; n < 16; ++n) {
    const int srow = n * 16 + r;
    short8 kf0 = *(const short8*)&Ks[srow * 64 + ((g) ^ (srow & 7)) * 8];
    short8 kf1 = *(const short8*)&Ks[srow * 64 + ((4 + g) ^ (srow & 7)) * 8];
#pragma unroll
    for (int m = 0; m < 2; ++m) {
      f32x4 acc = {0.f, 0.f, 0.f, 0.f};
      acc = mfma16(qf[m][0], kf0, acc);
      acc = mfma16(qf[m][1], kf1, acc);
#pragma unroll
      for (int i = 0; i < 4; ++i) {
        int rr = wv * 32 + m * 16 + g * 4 + i;
        int ss = n * 16 + r;
        bool valid = (ss >= rr + 1) && (ss <= rr + 128) && (qb > 0 || ss >= 128);
        float p = valid ? __expf(acc[i] * 0.125f) : 0.f;  // scores small: no max-sub needed
        rs[m][i] += p;
        Ps[rr * 264 + ss] = f2b(p);
      }
    }
  }
#pragma unroll
  for (int m = 0; m < 2; ++m)
#pragma unroll
    for (int i = 0; i < 4; ++i) {
      float v = rs[m][i];
      v += __shfl_xor(v, 1); v += __shfl_xor(v, 2);
      v += __shfl_xor(v, 4); v += __shfl_xor(v, 8);
      if (r == i) dn[wv * 32 + m * 16 + g * 4 + i] = v;
    }
  __syncthreads();

  f32x4 oacc[2][4] = {};
  for (int sc = 0; sc < 8; ++sc) {
    short8 pf[2], vf[4];
#pragma unroll
    for (int m = 0; m < 2; ++m)
      pf[m] = *(const short8*)&Ps[(wv * 32 + m * 16 + r) * 264 + sc * 32 + g * 8];
#pragma unroll
    for (int n = 0; n < 4; ++n)
      vf[n] = *(const short8*)&Vt[(n * 16 + r) * 264 + sc * 32 + g * 8];
#pragma unroll
    for (int m = 0; m < 2; ++m)
#pragma unroll
      for (int n = 0; n < 4; ++n)
        oacc[m][n] = mfma16(pf[m], vf[n], oacc[m][n]);
  }
#pragma unroll
  for (int m = 0; m < 2; ++m) {
    f32x4 dv = *(const f32x4*)&dn[wv * 32 + m * 16 + g * 4];
#pragma unroll
    for (int n = 0; n < 4; ++n) {
      int col = h * 64 + n * 16 + r;
#pragma unroll
      for (int i = 0; i < 4; ++i) {
        size_t row = (size_t)(tok0 + wv * 32 + m * 16 + g * 4 + i);
        outc[row * 2048 + col] = f2b(oacc[m][n][i] / dv[i]);
      }
    }
  }
}

// ---------------- Linear attention pass 1: per-chunk KVt[f][e], kz[e] ----------------
// qkv points at the S-half (fused buffer + 3072), row stride 6144.
__global__ __launch_bounds__(256) void lin_pass1(
    const unsigned short* __restrict__ qkv, float* __restrict__ KVt, float* __restrict__ kz) {
  __shared__ __attribute__((aligned(16))) unsigned short kf[128 * 72];
  __shared__ __attribute__((aligned(16))) unsigned short vs[128 * 72];
  __shared__ float kzp_s[4][64];
  const int bid = blockIdx.x;
  const int ch = bid & 31, h = (bid >> 5) & 15, b = bid >> 9;
  const size_t tok0 = (size_t)b * 4096 + (size_t)ch * 128;
  const int tid = threadIdx.x;
#pragma unroll
  for (int i = 0; i < 4; ++i) {
    int c = i * 256 + tid;
    int row = c >> 3, e8 = c & 7;
    u16x8 uk = *(const u16x8*)&qkv[(tok0 + row) * 6144 + 1024 + h * 64 + e8 * 8];
    u16x8 uv = *(const u16x8*)&qkv[(tok0 + row) * 6144 + 2048 + h * 64 + e8 * 8];
    u16x8 tk;
#pragma unroll
    for (int j = 0; j < 8; ++j) {
      tk[j] = f2b(elu_fast(b2f(uk[j])) + 1.0001f);
    }
    *(u16x8*)&kf[row * 72 + e8 * 8] = tk;
    *(u16x8*)&vs[row * 72 + e8 * 8] = uv;
  }
  __syncthreads();
  const int e0 = (tid & 15) * 4, f0 = (tid >> 4) * 4;
  float acc[4][4] = {};
  for (int c = 0; c < 128; ++c) {
    u16x4 ku = *(const u16x4*)&kf[c * 72 + e0];
    u16x4 vu = *(const u16x4*)&vs[c * 72 + f0];
    float ke[4], vv[4];
#pragma unroll
    for (int j = 0; j < 4; ++j) { ke[j] = b2f(ku[j]); vv[j] = b2f(vu[j]); }
#pragma unroll
    for (int jf = 0; jf < 4; ++jf)
#pragma unroll
      for (int je = 0; je < 4; ++je)
        acc[jf][je] += vv[jf] * ke[je];
  }
  const size_t base = (size_t)bid * 4096;
#pragma unroll
  for (int jf = 0; jf < 4; ++jf) {
    f32x4 o = {acc[jf][0], acc[jf][1], acc[jf][2], acc[jf][3]};
    *(f32x4*)&KVt[base + (f0 + jf) * 64 + e0] = o;
  }
  // kz tail: 4-way parallel over chunks (was: 64 threads x 128 serial iterations)
  {
    const int e = tid & 63, qq = tid >> 6;
    float s = 0.f;
    for (int c = qq * 32; c < qq * 32 + 32; ++c) s += b2f(kf[c * 72 + e]);
    kzp_s[qq][e] = s;
  }
  __syncthreads();
  if (tid < 64)
    kz[(size_t)bid * 64 + tid] = kzp_s[0][tid] + kzp_s[1][tid] + kzp_s[2][tid] + kzp_s[3][tid];
}

// ---------------- pass 2: per (b,h) exclusive prefix over 32 chunks (in place) -------------
// 128 blocks = 32 bh x 4 slices; per-chain order identical -> bit-identical results.
__global__ __launch_bounds__(256) void lin_pass2(float* __restrict__ KVt, float* __restrict__ kz) {
  const int bh = blockIdx.x >> 2, sl = blockIdx.x & 3;
  const int tid = threadIdx.x;
  const size_t eo = (size_t)(sl * 256 + tid) * 4;
  f32x4 run = {0.f, 0.f, 0.f, 0.f};
  for (int ch = 0; ch < 32; ++ch) {
    float* p = &KVt[((size_t)bh * 32 + ch) * 4096 + eo];
    f32x4 c = *(f32x4*)p;
    *(f32x4*)p = run;
    run += c;
  }
  if (sl == 0 && tid < 64) {
    float rz = 0.f;
    for (int ch = 0; ch < 32; ++ch) {
      float* p = &kz[((size_t)bh * 32 + ch) * 64 + tid];
      float c = *p; *p = rz; rz += c;
    }
  }
}

// ---------------- pass 3: o = (q@S_prev + tril(qk^T)@v) / (q.z_prev + rowsumA + 1e-6) ----------------
__global__ __launch_bounds__(256) void lin_pass3(
    const unsigned short* __restrict__ qkv, const float* __restrict__ KVt,
    const float* __restrict__ kz, unsigned short* __restrict__ outc) {
  __shared__ __attribute__((aligned(16))) unsigned short qf[128 * 72];
  __shared__ __attribute__((aligned(16))) unsigned short kf[128 * 72];
  __shared__ __attribute__((aligned(16))) unsigned short vt[64 * 136];
  __shared__ __attribute__((aligned(16))) unsigned short st[64 * 72];
  __shared__ __attribute__((aligned(16))) unsigned short am[128 * 136];
  __shared__ __attribute__((aligned(16))) float zs[64];
  __shared__ __attribute__((aligned(16))) float dnl[128];
  const int bid = blockIdx.x;
  const int ch = bid & 31, h = (bid >> 5) & 15, b = bid >> 9;
  const size_t tok0 = (size_t)b * 4096 + (size_t)ch * 128;
  const int tid = threadIdx.x, lane = tid & 63, wv = tid >> 6;
  const int g = lane >> 4, r = lane & 15;

#pragma unroll
  for (int i = 0; i < 4; ++i) {
    int c = i * 256 + tid;
    int row = c >> 3, e8 = c & 7;
    u16x8 uq = *(const u16x8*)&qkv[(tok0 + row) * 6144 + h * 64 + e8 * 8];
    u16x8 uk = *(const u16x8*)&qkv[(tok0 + row) * 6144 + 1024 + h * 64 + e8 * 8];
    u16x8 uv = *(const u16x8*)&qkv[(tok0 + row) * 6144 + 2048 + h * 64 + e8 * 8];
    u16x8 tq, tk;
#pragma unroll
    for (int j = 0; j < 8; ++j) {
      tq[j] = f2b(elu_fast(b2f(uq[j]) * 0.125f) + 1.0001f);
      tk[j] = f2b(elu_fast(b2f(uk[j])) + 1.0001f);
    }
    *(u16x8*)&qf[row * 72 + e8 * 8] = tq;
    *(u16x8*)&kf[row * 72 + e8 * 8] = tk;
#pragma unroll
    for (int j = 0; j < 8; ++j) vt[(e8 * 8 + j) * 136 + row] = uv[j];
  }
#pragma unroll
  for (int i = 0; i < 2; ++i) {  // S_prev^T (f-major) f32 -> bf16 LDS
    int idx = i * 256 + tid;
    int f = idx >> 3, e8 = idx & 7;
    f32x4 s0 = *(const f32x4*)&KVt[(size_t)bid * 4096 + f * 64 + e8 * 8];
    f32x4 s1 = *(const f32x4*)&KVt[(size_t)bid * 4096 + f * 64 + e8 * 8 + 4];
    u16x8 t;
#pragma unroll
    for (int j = 0; j < 4; ++j) { t[j] = f2b(s0[j]); t[4 + j] = f2b(s1[j]); }
    *(u16x8*)&st[f * 72 + e8 * 8] = t;
  }
  if (tid < 64) zs[tid] = kz[(size_t)bid * 64 + tid];
  __syncthreads();

  short8 aq[2][2];
#pragma unroll
  for (int m = 0; m < 2; ++m)
#pragma unroll
    for (int kc = 0; kc < 2; ++kc)
      aq[m][kc] = *(const short8*)&qf[(wv * 32 + m * 16 + r) * 72 + kc * 32 + g * 8];

  float rsA[2][4] = {};
  for (int n = 0; n < 8; ++n) {  // A = tril(qf @ kf^T), bf16 to LDS + rowsums
    short8 bk0 = *(const short8*)&kf[(n * 16 + r) * 72 + g * 8];
    short8 bk1 = *(const short8*)&kf[(n * 16 + r) * 72 + 32 + g * 8];
#pragma unroll
    for (int m = 0; m < 2; ++m) {
      f32x4 acc = {0.f, 0.f, 0.f, 0.f};
      acc = mfma16(aq[m][0], bk0, acc);
      acc = mfma16(aq[m][1], bk1, acc);
#pragma unroll
      for (int i = 0; i < 4; ++i) {
        int rr = wv * 32 + m * 16 + g * 4 + i;
        int cc = n * 16 + r;
        float v = (cc <= rr) ? acc[i] : 0.f;
        rsA[m][i] += v;
        am[rr * 136 + cc] = f2b(v);
      }
    }
  }
#pragma unroll
  for (int m = 0; m < 2; ++m)
#pragma unroll
    for (int i = 0; i < 4; ++i) {
      float v = rsA[m][i];
      v += __shfl_xor(v, 1); v += __shfl_xor(v, 2);
      v += __shfl_xor(v, 4); v += __shfl_xor(v, 8);
      if (r == i) dnl[wv * 32 + m * 16 + g * 4 + i] = v;
    }
  __syncthreads();

  if (tid < 128) {  // den = rowsumA + qf . z_prev
    float s = dnl[tid];
#pragma unroll
    for (int e = 0; e < 64; e += 4) {
      u16x4 qv = *(const u16x4*)&qf[tid * 72 + e];
      s += b2f(qv[0]) * zs[e] + b2f(qv[1]) * zs[e + 1] + b2f(qv[2]) * zs[e + 2] + b2f(qv[3]) * zs[e + 3];
    }
    dnl[tid] = s + 1e-6f;
  }

  f32x4 oac[2][4] = {};
#pragma unroll
  for (int kc = 0; kc < 2; ++kc) {  // num += qf @ S_prev
    short8 sf[4];
#pragma unroll
    for (int n = 0; n < 4; ++n) sf[n] = *(const short8*)&st[(n * 16 + r) * 72 + kc * 32 + g * 8];
#pragma unroll
    for (int m = 0; m < 2; ++m)
#pragma unroll
      for (int n = 0; n < 4; ++n)
        oac[m][n] = mfma16(aq[m][kc], sf[n], oac[m][n]);
  }
  for (int c4 = 0; c4 < 4; ++c4) {  // num += A @ v
    short8 pa[2], vb[4];
#pragma unroll
    for (int m = 0; m < 2; ++m)
      pa[m] = *(const short8*)&am[(wv * 32 + m * 16 + r) * 136 + c4 * 32 + g * 8];
#pragma unroll
    for (int n = 0; n < 4; ++n)
      vb[n] = *(const short8*)&vt[(n * 16 + r) * 136 + c4 * 32 + g * 8];
#pragma unroll
    for (int m = 0; m < 2; ++m)
#pragma unroll
      for (int n = 0; n < 4; ++n)
        oac[m][n] = mfma16(pa[m], vb[n], oac[m][n]);
  }
  __syncthreads();
#pragma unroll
  for (int m = 0; m < 2; ++m) {
    f32x4 dv = *(const f32x4*)&dnl[wv * 32 + m * 16 + g * 4];
#pragma unroll
    for (int n = 0; n < 4; ++n) {
      int col = 1024 + h * 64 + n * 16 + r;
#pragma unroll
      for (int i = 0; i < 4; ++i) {
        size_t row = tok0 + wv * 32 + m * 16 + g * 4 + i;
        outc[row * 2048 + col] = f2b(oac[m][n][i] / dv[i]);
      }
    }
  }
}

// ---------------- host ----------------
extern "C" void kernel_launch(void* const* d_in, const int* in_sizes, int n_in,
                              void* d_out, int out_size, void* d_ws, size_t ws_size,
                              hipStream_t stream) {
  (void)in_sizes; (void)n_in; (void)out_size; (void)ws_size;
  const float* x      = (const float*)d_in[0];
  const float* g1     = (const float*)d_in[1];
  const float* b1     = (const float*)d_in[2];
  const float* Wqkv_a = (const float*)d_in[3];
  const float* bqkv_a = (const float*)d_in[4];
  const float* Wp_a   = (const float*)d_in[5];
  const float* bp_a   = (const float*)d_in[6];
  const float* Wqkv_s = (const float*)d_in[7];
  const float* bqkv_s = (const float*)d_in[8];
  const float* Wo_s   = (const float*)d_in[9];
  const float* bo_s   = (const float*)d_in[10];
  const float* Wo     = (const float*)d_in[11];
  const float* bo     = (const float*)d_in[12];
  const float* gm     = (const float*)d_in[13];
  const float* bm     = (const float*)d_in[14];
  const float* W1     = (const float*)d_in[15];
  const float* b1m    = (const float*)d_in[16];
  const float* W2     = (const float*)d_in[17];
  const float* b2m    = (const float*)d_in[18];
  float* out = (float*)d_out;

  char* ws = (char*)d_ws;
  size_t off = 0;
  auto alloc = [&](size_t bytes) { char* p = ws + off; off += (bytes + 255) & ~(size_t)255; return p; };
  unsigned short* wTaS  = (unsigned short*)alloc((size_t)6144 * 1024 * 2);  // [Wqkv_a^T ; Wqkv_s^T]
  unsigned short* wTpo  = (unsigned short*)alloc((size_t)1024 * 2048 * 2);
  unsigned short* wTo   = (unsigned short*)alloc((size_t)1024 * 1024 * 2);
  unsigned short* wT1   = (unsigned short*)alloc((size_t)4096 * 1024 * 2);
  unsigned short* wT2   = (unsigned short*)alloc((size_t)1024 * 4096 * 2);
  float*          bcomb = (float*)alloc(1024 * 4);
  float*          bcat  = (float*)alloc(6144 * 4);
  unsigned short* xn    = (unsigned short*)alloc((size_t)8192 * 1024 * 2);  // reused as h
  unsigned short* qkvAS = (unsigned short*)alloc((size_t)8192 * 6144 * 2);  // fused; reused as gbuf
  unsigned short* comb  = (unsigned short*)alloc((size_t)8192 * 2048 * 2);  // reused as x1 (f32)
  float*          kvt   = (float*)alloc((size_t)1024 * 4096 * 4);           // reused as sum (bf16)
  float*          kzp   = (float*)alloc((size_t)1024 * 64 * 4);
  unsigned short* gbuf  = qkvAS;
  unsigned short* sum   = (unsigned short*)kvt;
  unsigned short* h_    = xn;
  float*          x1    = (float*)comb;  // comb dead once sum is computed

  // one batched dispatch for all 7 weight transposes
  TW7 tw;
  tw.S[0] = Wqkv_a; tw.D[0] = wTaS;                         tw.N[0] = 3072; tw.dld[0] = 1024; tw.doff[0] = 0;    tw.gx[0] = 16;
  tw.S[1] = Wqkv_s; tw.D[1] = wTaS + (size_t)3072 * 1024;   tw.N[1] = 3072; tw.dld[1] = 1024; tw.doff[1] = 0;    tw.gx[1] = 16;
  tw.S[2] = Wp_a;   tw.D[2] = wTpo;                         tw.N[2] = 1024; tw.dld[2] = 2048; tw.doff[2] = 0;    tw.gx[2] = 16;
  tw.S[3] = Wo_s;   tw.D[3] = wTpo;                         tw.N[3] = 1024; tw.dld[3] = 2048; tw.doff[3] = 1024; tw.gx[3] = 16;
  tw.S[4] = Wo;     tw.D[4] = wTo;                          tw.N[4] = 1024; tw.dld[4] = 1024; tw.doff[4] = 0;    tw.gx[4] = 16;
  tw.S[5] = W1;     tw.D[5] = wT1;                          tw.N[5] = 4096; tw.dld[5] = 1024; tw.doff[5] = 0;    tw.gx[5] = 16;
  tw.S[6] = W2;     tw.D[6] = wT2;                          tw.N[6] = 1024; tw.dld[6] = 4096; tw.doff[6] = 0;    tw.gx[6] = 64;
  tw.start[0] = 0;    tw.start[1] = 768;  tw.start[2] = 1536; tw.start[3] = 1792;
  tw.start[4] = 2048; tw.start[5] = 2304; tw.start[6] = 3328; tw.start[7] = 4352;
  transpose_w7<<<4352, 256, 0, stream>>>(tw);
  bias_prep<<<28, 256, 0, stream>>>(bp_a, bo_s, bqkv_a, bqkv_s, bcomb, bcat);

  ln_kernel<<<8192, 256, 0, stream>>>(x, g1, b1, xn);
  // fused QKV: M=8192, N=6144, K=1024 -> big 256x256, grid 32x24
  gemm_big<EPI_STORE, 0><<<dim3(32, 24), 512, 0, stream>>>(xn, wTaS, bcat, qkvAS, nullptr, 1024, 1024, 6144);
  swa_kernel<<<1024, 256, 0, stream>>>(qkvAS, comb);
  lin_pass1<<<1024, 256, 0, stream>>>(qkvAS + 3072, kvt, kzp);
  lin_pass2<<<128, 256, 0, stream>>>(kvt, kzp);
  lin_pass3<<<1024, 256, 0, stream>>>(qkvAS + 3072, kvt, kzp, comb);
  // sum = [attn|ssm] @ [Wp_a;Wo_s] + (bp_a+bo_s): M=8192,N=1024,K=2048 -> small, grid 64x4
  gemm_sml<EPI_STORE, 0><<<dim3(64, 4), 512, 0, stream>>>(comb, wTpo, bcomb, sum, nullptr, 2048, 2048, 1024);
  // x1 = x + sum @ Wo + bo (f32 out): M=8192,N=1024,K=1024
  gemm_sml<EPI_RES, 1><<<dim3(64, 4), 512, 0, stream>>>(sum, wTo, bo, x1, x, 1024, 1024, 1024);
  ln_kernel<<<8192, 256, 0, stream>>>(x1, gm, bm, h_);
  // MLP1: M=8192,N=4096,K=1024 -> big, grid 32x16
  gemm_big<EPI_GELU, 0><<<dim3(32, 16), 512, 0, stream>>>(h_, wT1, b1m, gbuf, nullptr, 1024, 1024, 4096);
  // MLP2: M=8192,N=1024,K=4096 -> small, grid 64x4
  gemm_sml<EPI_RES, 1><<<dim3(64, 4), 512, 0, stream>>>(gbuf, wT2, b2m, out, x1, 4096, 4096, 1024);
}